// Round 1
// baseline (211.065 us; speedup 1.0000x reference)
//
#include <hip/hip_runtime.h>

// Problem constants
#define SCALE 0.125f   // D^-0.5, D=64

typedef __bf16 bf16x8 __attribute__((ext_vector_type(8)));
typedef float f32x4 __attribute__((ext_vector_type(4)));

__device__ __forceinline__ ushort f2bf(float x) {
    union { float f; unsigned u; } v; v.f = x;
    unsigned r = v.u + 0x7FFFu + ((v.u >> 16) & 1u);  // RNE
    return (ushort)(r >> 16);
}

// ---------------- fp32 -> bf16 cast (memory-bound, vectorized) ----------------
__global__ __launch_bounds__(256) void cast_kernel(const float* __restrict__ src,
                                                   ushort* __restrict__ dst, int n4) {
    int i = blockIdx.x * 256 + threadIdx.x;
    if (i < n4) {
        float4 v = ((const float4*)src)[i];
        ushort4 o;
        o.x = f2bf(v.x); o.y = f2bf(v.y); o.z = f2bf(v.z); o.w = f2bf(v.w);
        ((ushort4*)dst)[i] = o;
    }
}

// ---------------- QKV projection GEMM ----------------
// A [4096][1024] bf16 (query rows r = l*2+n), B [3072][1024] bf16 (qkv_proj, B^T form)
// C[r][f] = sum_k A[r][k]*B[f][k] + bias[f]; f = i*3+which, i = h*64+d
// q -> qh[b=(n*16+h)][l][d] * SCALE ; k -> kh[b][l][d] ; v -> vT[b][d][l]
__global__ __launch_bounds__(256, 2) void gemm_qkv(
    const ushort* __restrict__ A, const ushort* __restrict__ B,
    const float* __restrict__ bias,
    ushort* __restrict__ qh, ushort* __restrict__ kh, ushort* __restrict__ vT)
{
    __shared__ ushort As[128][72];
    __shared__ ushort Bs[128][72];
    const int tid = threadIdx.x;
    const int lane = tid & 63, wave = tid >> 6;
    const int wr = (wave >> 1) * 64, wc = (wave & 1) * 64;
    const int lr = lane & 15, lg = lane >> 4;
    const int rowBase = blockIdx.y * 128, colBase = blockIdx.x * 128;

    f32x4 acc[4][4] = {};
    for (int k0 = 0; k0 < 1024; k0 += 64) {
        __syncthreads();
#pragma unroll
        for (int c = 0; c < 4; ++c) {
            int id = c * 256 + tid;
            int r = id >> 3, s = id & 7;
            *(int4*)&As[r][s * 8] = *(const int4*)(A + (size_t)(rowBase + r) * 1024 + k0 + s * 8);
            *(int4*)&Bs[r][s * 8] = *(const int4*)(B + (size_t)(colBase + r) * 1024 + k0 + s * 8);
        }
        __syncthreads();
#pragma unroll
        for (int kk = 0; kk < 2; ++kk) {
            bf16x8 af[4], bfr[4];
#pragma unroll
            for (int m = 0; m < 4; ++m)
                af[m] = *(const bf16x8*)&As[wr + m * 16 + lr][kk * 32 + lg * 8];
#pragma unroll
            for (int n = 0; n < 4; ++n)
                bfr[n] = *(const bf16x8*)&Bs[wc + n * 16 + lr][kk * 32 + lg * 8];
#pragma unroll
            for (int m = 0; m < 4; ++m)
#pragma unroll
                for (int n = 0; n < 4; ++n)
                    acc[m][n] = __builtin_amdgcn_mfma_f32_16x16x32_bf16(af[m], bfr[n], acc[m][n], 0, 0, 0);
        }
    }
#pragma unroll
    for (int n = 0; n < 4; ++n) {
        int f = colBase + wc + n * 16 + lr;
        float bv = bias[f];
        int which = f % 3;
        int i = f / 3;
        int h = i >> 6, d = i & 63;
#pragma unroll
        for (int m = 0; m < 4; ++m) {
#pragma unroll
            for (int j = 0; j < 4; ++j) {
                int row = rowBase + wr + m * 16 + lg * 4 + j;
                int l = row >> 1, nb = row & 1;
                int bh = nb * 16 + h;
                float v = acc[m][n][j] + bv;
                if (which == 0)      qh[((size_t)bh * 2048 + l) * 64 + d] = f2bf(v * SCALE);
                else if (which == 1) kh[((size_t)bh * 2048 + l) * 64 + d] = f2bf(v);
                else                 vT[((size_t)bh * 64 + d) * 2048 + l] = f2bf(v);
            }
        }
    }
}

// ---------------- Flash attention ----------------
// 32 batch-heads; per block: 64 q-rows (4 waves x 16), stream KV in tiles of 64.
__global__ __launch_bounds__(256, 2) void attn_kernel(
    const ushort* __restrict__ qh, const ushort* __restrict__ kh,
    const ushort* __restrict__ vT, ushort* __restrict__ attn_out)
{
    __shared__ ushort Ks[64][72];
    __shared__ ushort Vs[64][72];     // V^T tile: [d][m]
    __shared__ ushort Ps[4][16][72];  // per-wave P transpose buffer
    const int tid = threadIdx.x, lane = tid & 63, wave = tid >> 6;
    const int lr = lane & 15, lg = lane >> 4;
    const int b = blockIdx.y;
    const int qBase = blockIdx.x * 64;
    const int qrow = qBase + wave * 16 + lr;

    bf16x8 qf[2];
    qf[0] = *(const bf16x8*)(qh + ((size_t)b * 2048 + qrow) * 64 + lg * 8);
    qf[1] = *(const bf16x8*)(qh + ((size_t)b * 2048 + qrow) * 64 + 32 + lg * 8);

    f32x4 o[4] = {};
    float mrow[4] = {-1e30f, -1e30f, -1e30f, -1e30f};
    float lsum[4] = {0.f, 0.f, 0.f, 0.f};

    for (int t = 0; t < 32; ++t) {
        __syncthreads();
#pragma unroll
        for (int c = 0; c < 2; ++c) {
            int id = c * 256 + tid;
            int r = id >> 3, s = id & 7;
            *(int4*)&Ks[r][s * 8] = *(const int4*)(kh + ((size_t)b * 2048 + t * 64 + r) * 64 + s * 8);
            *(int4*)&Vs[r][s * 8] = *(const int4*)(vT + ((size_t)b * 64 + r) * 2048 + t * 64 + s * 8);
        }
        __syncthreads();

        // S = Q K^T  (rows = q, cols = m within tile)
        f32x4 sc[4] = {};
#pragma unroll
        for (int nt = 0; nt < 4; ++nt) {
#pragma unroll
            for (int kk = 0; kk < 2; ++kk) {
                bf16x8 kf = *(const bf16x8*)&Ks[nt * 16 + lr][kk * 32 + lg * 8];
                sc[nt] = __builtin_amdgcn_mfma_f32_16x16x32_bf16(qf[kk], kf, sc[nt], 0, 0, 0);
            }
        }
        // online softmax: rows owned = lg*4+j; reduce across 16 lanes (cols)
        float mx[4], alpha[4], rs[4];
#pragma unroll
        for (int j = 0; j < 4; ++j)
            mx[j] = fmaxf(fmaxf(sc[0][j], sc[1][j]), fmaxf(sc[2][j], sc[3][j]));
#pragma unroll
        for (int msk = 1; msk <= 8; msk <<= 1)
#pragma unroll
            for (int j = 0; j < 4; ++j)
                mx[j] = fmaxf(mx[j], __shfl_xor(mx[j], msk));
#pragma unroll
        for (int j = 0; j < 4; ++j) {
            float mn = fmaxf(mrow[j], mx[j]);
            alpha[j] = __expf(mrow[j] - mn);
            mrow[j] = mn;
            rs[j] = 0.f;
        }
#pragma unroll
        for (int nt = 0; nt < 4; ++nt)
#pragma unroll
            for (int j = 0; j < 4; ++j) {
                float p = __expf(sc[nt][j] - mrow[j]);
                sc[nt][j] = p;
                rs[j] += p;
            }
#pragma unroll
        for (int msk = 1; msk <= 8; msk <<= 1)
#pragma unroll
            for (int j = 0; j < 4; ++j)
                rs[j] += __shfl_xor(rs[j], msk);
#pragma unroll
        for (int j = 0; j < 4; ++j)
            lsum[j] = lsum[j] * alpha[j] + rs[j];
#pragma unroll
        for (int dt = 0; dt < 4; ++dt)
#pragma unroll
            for (int j = 0; j < 4; ++j)
                o[dt][j] *= alpha[j];

        // P -> LDS (wave-private) to get A-fragment layout
#pragma unroll
        for (int nt = 0; nt < 4; ++nt)
#pragma unroll
            for (int j = 0; j < 4; ++j)
                Ps[wave][lg * 4 + j][nt * 16 + lr] = f2bf(sc[nt][j]);

        // O += P V   (B operand from V^T tile: contiguous 16B reads)
#pragma unroll
        for (int kk = 0; kk < 2; ++kk) {
            bf16x8 pa = *(const bf16x8*)&Ps[wave][lr][kk * 32 + lg * 8];
#pragma unroll
            for (int dt = 0; dt < 4; ++dt) {
                bf16x8 vf = *(const bf16x8*)&Vs[dt * 16 + lr][kk * 32 + lg * 8];
                o[dt] = __builtin_amdgcn_mfma_f32_16x16x32_bf16(pa, vf, o[dt], 0, 0, 0);
            }
        }
    }

    const int nb = b >> 4, h = b & 15;
#pragma unroll
    for (int j = 0; j < 4; ++j) {
        int lq = qBase + wave * 16 + lg * 4 + j;
        float inv = 1.0f / lsum[j];
#pragma unroll
        for (int dt = 0; dt < 4; ++dt)
            attn_out[((size_t)(lq * 2 + nb)) * 1024 + h * 64 + dt * 16 + lr] = f2bf(o[dt][j] * inv);
    }
}

// ---------------- Output projection GEMM ----------------
// A = attn_out [4096][1024] bf16, B = out_proj [1024][1024] bf16 (B^T form), fp32 out + bias
__global__ __launch_bounds__(256, 2) void gemm_out(
    const ushort* __restrict__ A, const ushort* __restrict__ B,
    const float* __restrict__ bias, float* __restrict__ out)
{
    __shared__ ushort As[128][72];
    __shared__ ushort Bs[128][72];
    const int tid = threadIdx.x;
    const int lane = tid & 63, wave = tid >> 6;
    const int wr = (wave >> 1) * 64, wc = (wave & 1) * 64;
    const int lr = lane & 15, lg = lane >> 4;
    const int rowBase = blockIdx.y * 128, colBase = blockIdx.x * 128;

    f32x4 acc[4][4] = {};
    for (int k0 = 0; k0 < 1024; k0 += 64) {
        __syncthreads();
#pragma unroll
        for (int c = 0; c < 4; ++c) {
            int id = c * 256 + tid;
            int r = id >> 3, s = id & 7;
            *(int4*)&As[r][s * 8] = *(const int4*)(A + (size_t)(rowBase + r) * 1024 + k0 + s * 8);
            *(int4*)&Bs[r][s * 8] = *(const int4*)(B + (size_t)(colBase + r) * 1024 + k0 + s * 8);
        }
        __syncthreads();
#pragma unroll
        for (int kk = 0; kk < 2; ++kk) {
            bf16x8 af[4], bfr[4];
#pragma unroll
            for (int m = 0; m < 4; ++m)
                af[m] = *(const bf16x8*)&As[wr + m * 16 + lr][kk * 32 + lg * 8];
#pragma unroll
            for (int n = 0; n < 4; ++n)
                bfr[n] = *(const bf16x8*)&Bs[wc + n * 16 + lr][kk * 32 + lg * 8];
#pragma unroll
            for (int m = 0; m < 4; ++m)
#pragma unroll
                for (int n = 0; n < 4; ++n)
                    acc[m][n] = __builtin_amdgcn_mfma_f32_16x16x32_bf16(af[m], bfr[n], acc[m][n], 0, 0, 0);
        }
    }
#pragma unroll
    for (int n = 0; n < 4; ++n) {
        int e = colBase + wc + n * 16 + lr;
        float bv = bias[e];
#pragma unroll
        for (int m = 0; m < 4; ++m) {
#pragma unroll
            for (int j = 0; j < 4; ++j) {
                int row = rowBase + wr + m * 16 + lg * 4 + j;
                out[(size_t)row * 1024 + e] = acc[m][n][j] + bv;
            }
        }
    }
}

extern "C" void kernel_launch(void* const* d_in, const int* in_sizes, int n_in,
                              void* d_out, int out_size, void* d_ws, size_t ws_size,
                              hipStream_t stream) {
    const float* query    = (const float*)d_in[0];
    const float* qkv_proj = (const float*)d_in[1];
    const float* qkv_bias = (const float*)d_in[2];
    const float* out_proj = (const float*)d_in[3];
    const float* out_bias = (const float*)d_in[4];
    float* out = (float*)d_out;

    char* ws = (char*)d_ws;
    ushort* qbf      = (ushort*)ws;                      // 8 MB  query bf16 [4096][1024]
    ushort* wqkv     = (ushort*)(ws + (8ull << 20));     // 6 MB  qkv_proj bf16 [3072][1024]
    ushort* wout     = (ushort*)(ws + (14ull << 20));    // 2 MB  out_proj bf16 [1024][1024]
    ushort* qh       = (ushort*)(ws + (16ull << 20));    // 8 MB  [32][2048][64]
    ushort* kh       = (ushort*)(ws + (24ull << 20));    // 8 MB  [32][2048][64]
    ushort* vT       = (ushort*)(ws + (32ull << 20));    // 8 MB  [32][64][2048]
    ushort* attn_out = (ushort*)(ws + (40ull << 20));    // 8 MB  [4096][1024]

    cast_kernel<<<4096, 256, 0, stream>>>(query, qbf, 1048576);
    cast_kernel<<<3072, 256, 0, stream>>>(qkv_proj, wqkv, 786432);
    cast_kernel<<<1024, 256, 0, stream>>>(out_proj, wout, 262144);
    gemm_qkv<<<dim3(24, 32), 256, 0, stream>>>(qbf, wqkv, qkv_bias, qh, kh, vT);
    attn_kernel<<<dim3(32, 32), 256, 0, stream>>>(qh, kh, vT, attn_out);
    gemm_out<<<dim3(8, 32), 256, 0, stream>>>(attn_out, wout, out_bias, out);
}

// Round 2
// 158.480 us; speedup vs baseline: 1.3318x; 1.3318x over previous
//
#include <hip/hip_runtime.h>
#include <stdint.h>

#define SCALE 0.125f   // D^-0.5, D=64
#define LOG2E 1.44269504088896340736f
#define QK_SCALE (SCALE * LOG2E)   // S in log2 domain -> bare v_exp_f32

typedef __bf16 bf16x8 __attribute__((ext_vector_type(8)));
typedef float f32x4 __attribute__((ext_vector_type(4)));
typedef unsigned u32x4 __attribute__((ext_vector_type(4)));

__device__ __forceinline__ ushort f2bf(float x) {
    union { float f; unsigned u; } v; v.f = x;
    unsigned r = v.u + 0x7FFFu + ((v.u >> 16) & 1u);  // RNE
    return (ushort)(r >> 16);
}

// async 16B global->LDS (CK-style addrspace cast: generic LDS addr low 32 bits == AS3 offset)
__device__ __forceinline__ void gld_lds16(const void* g, void* l) {
    __builtin_amdgcn_global_load_lds(
        reinterpret_cast<const unsigned __attribute__((address_space(1)))*>(
            reinterpret_cast<uintptr_t>(g)),
        reinterpret_cast<unsigned __attribute__((address_space(3)))*>(
            (unsigned)reinterpret_cast<uintptr_t>(l)),
        16, 0, 0);
}

// ---------------- fp32 -> bf16 cast ----------------
__global__ __launch_bounds__(256) void cast_kernel(const float* __restrict__ src,
                                                   ushort* __restrict__ dst, int n4) {
    int i = blockIdx.x * 256 + threadIdx.x;
    if (i < n4) {
        float4 v = ((const float4*)src)[i];
        ushort4 o;
        o.x = f2bf(v.x); o.y = f2bf(v.y); o.z = f2bf(v.z); o.w = f2bf(v.w);
        ((ushort4*)dst)[i] = o;
    }
}

// ---------------- QKV projection GEMM (128x128 tile, BK=64, gld_lds + T2 swizzle) ----------------
__global__ __launch_bounds__(256, 2) void gemm_qkv(
    const ushort* __restrict__ A, const ushort* __restrict__ B,
    const float* __restrict__ bias,
    ushort* __restrict__ qh, ushort* __restrict__ kh, ushort* __restrict__ vT)
{
    __shared__ ushort As[128][64];
    __shared__ ushort Bs[128][64];
    const int tid = threadIdx.x;
    const int lane = tid & 63, wave = tid >> 6;
    const int wr = (wave >> 1) * 64, wc = (wave & 1) * 64;
    const int lr = lane & 15, lg = lane >> 4;
    const int swz = (lr & 7) << 4;
    const int sl = lane >> 3;                  // row within 8-row slab
    const int scol = ((lane & 7) ^ sl) * 8;    // pre-swizzled source col (ushort)
    const int rowBase = blockIdx.y * 128, colBase = blockIdx.x * 128;

    f32x4 acc[4][4] = {};
    for (int k0 = 0; k0 < 1024; k0 += 64) {
        __syncthreads();
        int s0 = wave * 4;
#pragma unroll
        for (int i = 0; i < 4; ++i) {
            int s = s0 + i;
            gld_lds16(A + (size_t)(rowBase + s * 8 + sl) * 1024 + k0 + scol, &As[s * 8][0]);
            gld_lds16(B + (size_t)(colBase + s * 8 + sl) * 1024 + k0 + scol, &Bs[s * 8][0]);
        }
        __syncthreads();
#pragma unroll
        for (int kk = 0; kk < 2; ++kk) {
            bf16x8 af[4], bfr[4];
#pragma unroll
            for (int m = 0; m < 4; ++m)
                af[m] = *(const bf16x8*)((const char*)As + (wr + m * 16 + lr) * 128 + ((kk * 64 + lg * 16) ^ swz));
#pragma unroll
            for (int n = 0; n < 4; ++n)
                bfr[n] = *(const bf16x8*)((const char*)Bs + (wc + n * 16 + lr) * 128 + ((kk * 64 + lg * 16) ^ swz));
#pragma unroll
            for (int m = 0; m < 4; ++m)
#pragma unroll
                for (int n = 0; n < 4; ++n)
                    acc[m][n] = __builtin_amdgcn_mfma_f32_16x16x32_bf16(af[m], bfr[n], acc[m][n], 0, 0, 0);
        }
    }
#pragma unroll
    for (int n = 0; n < 4; ++n) {
        int f = colBase + wc + n * 16 + lr;
        float bv = bias[f];
        int which = f % 3;
        int i = f / 3;
        int h = i >> 6, d = i & 63;
#pragma unroll
        for (int m = 0; m < 4; ++m) {
#pragma unroll
            for (int j = 0; j < 4; ++j) {
                int row = rowBase + wr + m * 16 + lg * 4 + j;
                int l = row >> 1, nb = row & 1;
                int bh = nb * 16 + h;
                float v = acc[m][n][j] + bv;
                if (which == 0)      qh[((size_t)bh * 2048 + l) * 64 + d] = f2bf(v * QK_SCALE);
                else if (which == 1) kh[((size_t)bh * 2048 + l) * 64 + d] = f2bf(v);
                else                 vT[((size_t)bh * 64 + d) * 2048 + l] = f2bf(v);
            }
        }
    }
}

// ---------------- Flash attention: swapped QK^T, in-register P redistribution ----------------
__global__ __launch_bounds__(256, 4) void attn_kernel(
    const ushort* __restrict__ qh, const ushort* __restrict__ kh,
    const ushort* __restrict__ vT, ushort* __restrict__ attn_out)
{
    __shared__ ushort Ks[2][64][64];
    __shared__ ushort Vs[2][64][64];   // V^T tile: [d][kv]
    const int tid = threadIdx.x, lane = tid & 63, wave = tid >> 6;
    const int lr = lane & 15, lg = lane >> 4;
    const int beta = (lane >> 5) & 1;
    const int swz = (lr & 7) << 4;
    // lane-bit4<->bit5 swap permutation, byte address for ds_bpermute
    const int bperm_addr = (((lane & 15) | ((lane & 16) << 1) | ((lane & 32) >> 1)) << 2);
    const int b = blockIdx.y;
    const int qBase = blockIdx.x * 64;
    const int qrow = qBase + wave * 16 + lr;
    const int sl = lane >> 3;
    const int scol = ((lane & 7) ^ sl) * 8;
    const size_t kBase = (size_t)b * 2048;
    const size_t vBase = (size_t)b * 64;

    bf16x8 qf[2];
    qf[0] = *(const bf16x8*)(qh + (kBase + qrow) * 64 + lg * 8);
    qf[1] = *(const bf16x8*)(qh + (kBase + qrow) * 64 + 32 + lg * 8);

    f32x4 o[4] = {};
    float mrun = -1e30f, lsum = 0.f;

    // prologue: stage tile 0 into buf 0
    {
        int s0 = wave * 2;
#pragma unroll
        for (int i = 0; i < 2; ++i) {
            int s = s0 + i;
            gld_lds16(kh + (kBase + s * 8 + sl) * 64 + scol, &Ks[0][s * 8][0]);
            gld_lds16(vT + (vBase + s * 8 + sl) * 2048 + scol, &Vs[0][s * 8][0]);
        }
    }
    __syncthreads();

    int buf = 0;
    for (int t = 0; t < 32; ++t) {
        if (t < 31) {  // issue next tile's stage before compute (latency hides under MFMA/softmax)
            int s0 = wave * 2;
#pragma unroll
            for (int i = 0; i < 2; ++i) {
                int s = s0 + i;
                gld_lds16(kh + (kBase + (t + 1) * 64 + s * 8 + sl) * 64 + scol, &Ks[buf ^ 1][s * 8][0]);
                gld_lds16(vT + (vBase + s * 8 + sl) * 2048 + (t + 1) * 64 + scol, &Vs[buf ^ 1][s * 8][0]);
            }
        }
        const char* kb = (const char*)Ks + buf * 8192;
        const char* vb = (const char*)Vs + buf * 8192;

        // S^T = K Q^T : lane holds S[q=lr][kv = nt*16 + lg*4 + j]
        f32x4 sc[4] = {};
        __builtin_amdgcn_s_setprio(1);
#pragma unroll
        for (int nt = 0; nt < 4; ++nt) {
#pragma unroll
            for (int kk = 0; kk < 2; ++kk) {
                bf16x8 kf = *(const bf16x8*)(kb + (nt * 16 + lr) * 128 + ((kk * 64 + lg * 16) ^ swz));
                sc[nt] = __builtin_amdgcn_mfma_f32_16x16x32_bf16(kf, qf[kk], sc[nt], 0, 0, 0);
            }
        }
        __builtin_amdgcn_s_setprio(0);

        // online softmax (log2 domain), row = lr, reduce over lg group
        float mx = sc[0][0];
#pragma unroll
        for (int nt = 0; nt < 4; ++nt)
#pragma unroll
            for (int j = 0; j < 4; ++j)
                mx = fmaxf(mx, sc[nt][j]);
        mx = fmaxf(mx, __shfl_xor(mx, 16));
        mx = fmaxf(mx, __shfl_xor(mx, 32));
        if (!__all(mx - mrun <= 8.0f)) {   // defer-max (T13)
            float mnew = fmaxf(mrun, mx);
            float alpha = __builtin_amdgcn_exp2f(mrun - mnew);
            mrun = mnew;
            lsum *= alpha;
#pragma unroll
            for (int dt = 0; dt < 4; ++dt) o[dt] *= alpha;
        }
        float rs = 0.f;
#pragma unroll
        for (int nt = 0; nt < 4; ++nt)
#pragma unroll
            for (int j = 0; j < 4; ++j) {
                float p = __builtin_amdgcn_exp2f(sc[nt][j] - mrun);
                sc[nt][j] = p;
                rs += p;
            }
        rs += __shfl_xor(rs, 16);
        rs += __shfl_xor(rs, 32);
        lsum += rs;

        // P (f32, per-lane) -> bf16 B-fragments, fully in-register (no LDS):
        // step 1: cvt_pk pairs, then swap lane bits 4<->5 (ds_bpermute)
        unsigned W1[4][2];
#pragma unroll
        for (int nt = 0; nt < 4; ++nt)
#pragma unroll
            for (int jh = 0; jh < 2; ++jh) {
                unsigned w;
                asm("v_cvt_pk_bf16_f32 %0, %1, %2" : "=v"(w) : "v"(sc[nt][2 * jh]), "v"(sc[nt][2 * jh + 1]));
                W1[nt][jh] = (unsigned)__builtin_amdgcn_ds_bpermute(bperm_addr, (int)w);
            }
        // step 2: cross-half exchange; pb[kk] = B-frag (kv = kk*32 + lg'*8 + m)
        __builtin_amdgcn_s_setprio(1);
#pragma unroll
        for (int kk = 0; kk < 2; ++kk) {
            unsigned A0 = W1[2 * kk][0], A1 = W1[2 * kk][1];
            unsigned B0 = W1[2 * kk + 1][0], B1 = W1[2 * kk + 1][1];
            unsigned E0 = beta ? A0 : B0, E1 = beta ? A1 : B1;
            unsigned F0 = (unsigned)__shfl_xor((int)E0, 32);
            unsigned F1 = (unsigned)__shfl_xor((int)E1, 32);
            u32x4 pw;
            pw[0] = beta ? F0 : A0;
            pw[1] = beta ? F1 : A1;
            pw[2] = beta ? B0 : F0;
            pw[3] = beta ? B1 : F1;
            bf16x8 pb = __builtin_bit_cast(bf16x8, pw);
#pragma unroll
            for (int dt = 0; dt < 4; ++dt) {   // O^T = V^T P^T
                bf16x8 vf = *(const bf16x8*)(vb + (dt * 16 + lr) * 128 + ((kk * 64 + lg * 16) ^ swz));
                o[dt] = __builtin_amdgcn_mfma_f32_16x16x32_bf16(vf, pb, o[dt], 0, 0, 0);
            }
        }
        __builtin_amdgcn_s_setprio(0);
        __syncthreads();
        buf ^= 1;
    }

    // epilogue: lane holds O^T[d = dt*16 + lg*4 + j][q = lr]
    const int nb = b >> 4, h = b & 15;
    float inv = __builtin_amdgcn_rcpf(lsum);
    const size_t row = (size_t)(qBase + wave * 16 + lr) * 2 + nb;
#pragma unroll
    for (int dt = 0; dt < 4; ++dt) {
        float a0 = o[dt][0] * inv, a1 = o[dt][1] * inv;
        float a2 = o[dt][2] * inv, a3 = o[dt][3] * inv;
        unsigned w0, w1;
        asm("v_cvt_pk_bf16_f32 %0, %1, %2" : "=v"(w0) : "v"(a0), "v"(a1));
        asm("v_cvt_pk_bf16_f32 %0, %1, %2" : "=v"(w1) : "v"(a2), "v"(a3));
        uint2 st; st.x = w0; st.y = w1;
        *(uint2*)(attn_out + row * 1024 + h * 64 + dt * 16 + lg * 4) = st;
    }
}

// ---------------- Output projection GEMM ----------------
__global__ __launch_bounds__(256, 2) void gemm_out(
    const ushort* __restrict__ A, const ushort* __restrict__ B,
    const float* __restrict__ bias, float* __restrict__ out)
{
    __shared__ ushort As[128][64];
    __shared__ ushort Bs[128][64];
    const int tid = threadIdx.x;
    const int lane = tid & 63, wave = tid >> 6;
    const int wr = (wave >> 1) * 64, wc = (wave & 1) * 64;
    const int lr = lane & 15, lg = lane >> 4;
    const int swz = (lr & 7) << 4;
    const int sl = lane >> 3;
    const int scol = ((lane & 7) ^ sl) * 8;
    const int rowBase = blockIdx.y * 128, colBase = blockIdx.x * 128;

    f32x4 acc[4][4] = {};
    for (int k0 = 0; k0 < 1024; k0 += 64) {
        __syncthreads();
        int s0 = wave * 4;
#pragma unroll
        for (int i = 0; i < 4; ++i) {
            int s = s0 + i;
            gld_lds16(A + (size_t)(rowBase + s * 8 + sl) * 1024 + k0 + scol, &As[s * 8][0]);
            gld_lds16(B + (size_t)(colBase + s * 8 + sl) * 1024 + k0 + scol, &Bs[s * 8][0]);
        }
        __syncthreads();
#pragma unroll
        for (int kk = 0; kk < 2; ++kk) {
            bf16x8 af[4], bfr[4];
#pragma unroll
            for (int m = 0; m < 4; ++m)
                af[m] = *(const bf16x8*)((const char*)As + (wr + m * 16 + lr) * 128 + ((kk * 64 + lg * 16) ^ swz));
#pragma unroll
            for (int n = 0; n < 4; ++n)
                bfr[n] = *(const bf16x8*)((const char*)Bs + (wc + n * 16 + lr) * 128 + ((kk * 64 + lg * 16) ^ swz));
#pragma unroll
            for (int m = 0; m < 4; ++m)
#pragma unroll
                for (int n = 0; n < 4; ++n)
                    acc[m][n] = __builtin_amdgcn_mfma_f32_16x16x32_bf16(af[m], bfr[n], acc[m][n], 0, 0, 0);
        }
    }
#pragma unroll
    for (int n = 0; n < 4; ++n) {
        int e = colBase + wc + n * 16 + lr;
        float bv = bias[e];
#pragma unroll
        for (int m = 0; m < 4; ++m) {
#pragma unroll
            for (int j = 0; j < 4; ++j) {
                int row = rowBase + wr + m * 16 + lg * 4 + j;
                out[(size_t)row * 1024 + e] = acc[m][n][j] + bv;
            }
        }
    }
}

extern "C" void kernel_launch(void* const* d_in, const int* in_sizes, int n_in,
                              void* d_out, int out_size, void* d_ws, size_t ws_size,
                              hipStream_t stream) {
    const float* query    = (const float*)d_in[0];
    const float* qkv_proj = (const float*)d_in[1];
    const float* qkv_bias = (const float*)d_in[2];
    const float* out_proj = (const float*)d_in[3];
    const float* out_bias = (const float*)d_in[4];
    float* out = (float*)d_out;

    char* ws = (char*)d_ws;
    ushort* qbf      = (ushort*)ws;                      // 8 MB  query bf16 [4096][1024]
    ushort* wqkv     = (ushort*)(ws + (8ull << 20));     // 6 MB  qkv_proj bf16 [3072][1024]
    ushort* wout     = (ushort*)(ws + (14ull << 20));    // 2 MB  out_proj bf16 [1024][1024]
    ushort* qh       = (ushort*)(ws + (16ull << 20));    // 8 MB  [32][2048][64] (pre-scaled by SCALE*LOG2E)
    ushort* kh       = (ushort*)(ws + (24ull << 20));    // 8 MB  [32][2048][64]
    ushort* vT       = (ushort*)(ws + (32ull << 20));    // 8 MB  [32][64][2048]
    ushort* attn_out = (ushort*)(ws + (40ull << 20));    // 8 MB  [4096][1024]

    cast_kernel<<<4096, 256, 0, stream>>>(query, qbf, 1048576);
    cast_kernel<<<3072, 256, 0, stream>>>(qkv_proj, wqkv, 786432);
    cast_kernel<<<1024, 256, 0, stream>>>(out_proj, wout, 262144);
    gemm_qkv<<<dim3(24, 32), 256, 0, stream>>>(qbf, wqkv, qkv_bias, qh, kh, vT);
    attn_kernel<<<dim3(32, 32), 256, 0, stream>>>(qh, kh, vT, attn_out);
    gemm_out<<<dim3(8, 32), 256, 0, stream>>>(attn_out, wout, out_bias, out);
}

// Round 4
// 145.134 us; speedup vs baseline: 1.4543x; 1.0920x over previous
//
#include <hip/hip_runtime.h>
#include <stdint.h>

#define SCALE 0.125f   // D^-0.5, D=64
#define LOG2E 1.44269504088896340736f
#define QK_SCALE (SCALE * LOG2E)   // S in log2 domain -> bare v_exp_f32

typedef __bf16 bf16x8 __attribute__((ext_vector_type(8)));
typedef float f32x4 __attribute__((ext_vector_type(4)));
typedef float f32x16 __attribute__((ext_vector_type(16)));
typedef unsigned u32x4 __attribute__((ext_vector_type(4)));

__device__ __forceinline__ ushort f2bf(float x) {
    union { float f; unsigned u; } v; v.f = x;
    unsigned r = v.u + 0x7FFFu + ((v.u >> 16) & 1u);  // RNE
    return (ushort)(r >> 16);
}

// async 16B global->LDS
__device__ __forceinline__ void gld_lds16(const void* g, void* l) {
    __builtin_amdgcn_global_load_lds(
        reinterpret_cast<const unsigned __attribute__((address_space(1)))*>(
            reinterpret_cast<uintptr_t>(g)),
        reinterpret_cast<unsigned __attribute__((address_space(3)))*>(
            (unsigned)reinterpret_cast<uintptr_t>(l)),
        16, 0, 0);
}

// ---------------- fp32 -> bf16 cast ----------------
__global__ __launch_bounds__(256) void cast_kernel(const float* __restrict__ src,
                                                   ushort* __restrict__ dst, int n4) {
    int i = blockIdx.x * 256 + threadIdx.x;
    if (i < n4) {
        float4 v = ((const float4*)src)[i];
        ushort4 o;
        o.x = f2bf(v.x); o.y = f2bf(v.y); o.z = f2bf(v.z); o.w = f2bf(v.w);
        ((ushort4*)dst)[i] = o;
    }
}

// ---------------- QKV projection GEMM ----------------
__global__ __launch_bounds__(256, 3) void gemm_qkv(
    const ushort* __restrict__ A, const ushort* __restrict__ B,
    const float* __restrict__ bias,
    ushort* __restrict__ qh, ushort* __restrict__ kh, ushort* __restrict__ vT)
{
    __shared__ ushort As[128][64];
    __shared__ ushort Bs[128][64];
    const int tid = threadIdx.x;
    const int lane = tid & 63, wave = tid >> 6;
    const int wr = (wave >> 1) * 64, wc = (wave & 1) * 64;
    const int lr = lane & 15, lg = lane >> 4;
    const int swz = (lr & 7) << 4;
    const int sl = lane >> 3;
    const int scol = ((lane & 7) ^ sl) * 8;
    const int rowBase = blockIdx.y * 128, colBase = blockIdx.x * 128;

    f32x4 acc[4][4] = {};
    for (int k0 = 0; k0 < 1024; k0 += 64) {
        __syncthreads();
        int s0 = wave * 4;
#pragma unroll
        for (int i = 0; i < 4; ++i) {
            int s = s0 + i;
            gld_lds16(A + (size_t)(rowBase + s * 8 + sl) * 1024 + k0 + scol, &As[s * 8][0]);
            gld_lds16(B + (size_t)(colBase + s * 8 + sl) * 1024 + k0 + scol, &Bs[s * 8][0]);
        }
        __syncthreads();
#pragma unroll
        for (int kk = 0; kk < 2; ++kk) {
            bf16x8 af[4], bfr[4];
#pragma unroll
            for (int m = 0; m < 4; ++m)
                af[m] = *(const bf16x8*)((const char*)As + (wr + m * 16 + lr) * 128 + ((kk * 64 + lg * 16) ^ swz));
#pragma unroll
            for (int n = 0; n < 4; ++n)
                bfr[n] = *(const bf16x8*)((const char*)Bs + (wc + n * 16 + lr) * 128 + ((kk * 64 + lg * 16) ^ swz));
#pragma unroll
            for (int m = 0; m < 4; ++m)
#pragma unroll
                for (int n = 0; n < 4; ++n)
                    acc[m][n] = __builtin_amdgcn_mfma_f32_16x16x32_bf16(af[m], bfr[n], acc[m][n], 0, 0, 0);
        }
    }
#pragma unroll
    for (int n = 0; n < 4; ++n) {
        int f = colBase + wc + n * 16 + lr;
        float bv = bias[f];
        int which = f % 3;
        int i = f / 3;
        int h = i >> 6, d = i & 63;
#pragma unroll
        for (int m = 0; m < 4; ++m) {
#pragma unroll
            for (int j = 0; j < 4; ++j) {
                int row = rowBase + wr + m * 16 + lg * 4 + j;
                int l = row >> 1, nb = row & 1;
                int bh = nb * 16 + h;
                float v = acc[m][n][j] + bv;
                if (which == 0)      qh[((size_t)bh * 2048 + l) * 64 + d] = f2bf(v * QK_SCALE);
                else if (which == 1) kh[((size_t)bh * 2048 + l) * 64 + d] = f2bf(v);
                else                 vT[((size_t)bh * 64 + d) * 2048 + l] = f2bf(v);
            }
        }
    }
}

// ---------------- Flash attention: 32x32 MFMA, lane-local softmax rows ----------------
// Block: 4 waves x 32 q = 128 q-rows. KV tiles of 64, double-buffered.
// sc[blk] = mfma_32x32x16(K-frag, Q-frag): lane holds S^T[kv][q=lane&31],
//   kv = blk*32 + (r&3) + 8*(r>>2) + 4*hi  (r = reg 0..15, hi = lane>>5)
// Cross-half exchanges via __shfl_xor(.,32) (proven in R2) — no permlane.
__global__ __launch_bounds__(256, 2) void attn_kernel(
    const ushort* __restrict__ qh, const ushort* __restrict__ kh,
    const ushort* __restrict__ vT, ushort* __restrict__ attn_out)
{
    __shared__ ushort Ks[2][64][64];
    __shared__ ushort Vs[2][64][64];   // V^T tile: [d][kv]
    const int tid = threadIdx.x, lane = tid & 63, wave = tid >> 6;
    const int l31 = lane & 31, hi = lane >> 5;
    const int swz = (lane & 7) << 4;   // row&7 == lane&7 for rows = blk*32 + l31
    const int b = blockIdx.y;
    const int qBase = blockIdx.x * 128;
    const int qrow = qBase + wave * 32 + l31;
    const int sl = lane >> 3;
    const int scol = ((lane & 7) ^ sl) * 8;
    const size_t kBase = (size_t)b * 2048;
    const size_t vBase = (size_t)b * 64;

    // Q B-fragments (col=q=lane&31, k = kk*16 + hi*8 + e), persistent
    bf16x8 qf[4];
#pragma unroll
    for (int kk = 0; kk < 4; ++kk)
        qf[kk] = *(const bf16x8*)(qh + (kBase + qrow) * 64 + kk * 16 + hi * 8);

    f32x16 ot[2] = {};
    float mrun = -1e30f, lsum = 0.f;

    // prologue: stage tile 0 into buf 0
    {
        int s0 = wave * 2;
#pragma unroll
        for (int i = 0; i < 2; ++i) {
            int s = s0 + i;
            gld_lds16(kh + (kBase + s * 8 + sl) * 64 + scol, &Ks[0][s * 8][0]);
            gld_lds16(vT + (vBase + s * 8 + sl) * 2048 + scol, &Vs[0][s * 8][0]);
        }
    }
    __syncthreads();

    int buf = 0;
    for (int t = 0; t < 32; ++t) {
        if (t < 31) {
            int s0 = wave * 2;
#pragma unroll
            for (int i = 0; i < 2; ++i) {
                int s = s0 + i;
                gld_lds16(kh + (kBase + (t + 1) * 64 + s * 8 + sl) * 64 + scol, &Ks[buf ^ 1][s * 8][0]);
                gld_lds16(vT + (vBase + s * 8 + sl) * 2048 + (t + 1) * 64 + scol, &Vs[buf ^ 1][s * 8][0]);
            }
        }
        const char* kb = (const char*)Ks + buf * 8192;
        const char* vb = (const char*)Vs + buf * 8192;

        // S^T = K Q^T
        f32x16 sc[2] = {};
        __builtin_amdgcn_s_setprio(1);
#pragma unroll
        for (int blk = 0; blk < 2; ++blk) {
#pragma unroll
            for (int kk = 0; kk < 4; ++kk) {
                bf16x8 kf = *(const bf16x8*)(kb + (blk * 32 + l31) * 128 + ((kk * 32 + hi * 16) ^ swz));
                sc[blk] = __builtin_amdgcn_mfma_f32_32x32x16_bf16(kf, qf[kk], sc[blk], 0, 0, 0);
            }
        }
        __builtin_amdgcn_s_setprio(0);

        // lane-local row max over 32 values + cross-half combine (shfl_xor 32)
        float mx = sc[0][0];
#pragma unroll
        for (int blk = 0; blk < 2; ++blk)
#pragma unroll
            for (int r = 0; r < 16; ++r)
                mx = fmaxf(mx, sc[blk][r]);
        mx = fmaxf(mx, __shfl_xor(mx, 32));
        if (!__all(mx - mrun <= 8.0f)) {   // defer-max (T13)
            float mnew = fmaxf(mrun, mx);
            float alpha = __builtin_amdgcn_exp2f(mrun - mnew);
            mrun = mnew;
            lsum *= alpha;
#pragma unroll
            for (int blk = 0; blk < 2; ++blk)
#pragma unroll
                for (int r = 0; r < 16; ++r)
                    ot[blk][r] *= alpha;
        }
        float rs = 0.f;
#pragma unroll
        for (int blk = 0; blk < 2; ++blk)
#pragma unroll
            for (int r = 0; r < 16; ++r) {
                float p = __builtin_amdgcn_exp2f(sc[blk][r] - mrun);
                sc[blk][r] = p;
                rs += p;
            }
        rs += __shfl_xor(rs, 32);
        lsum += rs;

        // P -> B-frags + PV. Target lane (l31,hi), group g: pb[e] = P[q=l31][kv=g*16+hi*8+e].
        // Source (blk, m) = ((2g+hi)>>2, (2g+hi)&3); e<4 from hi'=0 lane, e>=4 from hi'=1 lane.
        // blk = g>>1 for both hi; m = m0+hi with m0 = (g&1)*2.
        __builtin_amdgcn_s_setprio(1);
#pragma unroll
        for (int g = 0; g < 4; ++g) {
            const int blk = g >> 1;
            const int base = (g & 1) * 8;   // = 4*m0
            unsigned A0, A1, B0, B1;
            asm("v_cvt_pk_bf16_f32 %0, %1, %2" : "=v"(A0) : "v"(sc[blk][base + 0]), "v"(sc[blk][base + 1]));
            asm("v_cvt_pk_bf16_f32 %0, %1, %2" : "=v"(A1) : "v"(sc[blk][base + 2]), "v"(sc[blk][base + 3]));
            asm("v_cvt_pk_bf16_f32 %0, %1, %2" : "=v"(B0) : "v"(sc[blk][base + 4]), "v"(sc[blk][base + 5]));
            asm("v_cvt_pk_bf16_f32 %0, %1, %2" : "=v"(B1) : "v"(sc[blk][base + 6]), "v"(sc[blk][base + 7]));
            // exchange: hi=0 sends B (m1) to partner, needs partner's A (m0); hi=1 vice versa
            unsigned send0 = hi ? A0 : B0, send1 = hi ? A1 : B1;
            unsigned recv0 = (unsigned)__shfl_xor((int)send0, 32);
            unsigned recv1 = (unsigned)__shfl_xor((int)send1, 32);
            u32x4 pw;
            pw[0] = hi ? recv0 : A0;   // e0,e1 (from hi'=0 source)
            pw[1] = hi ? recv1 : A1;   // e2,e3
            pw[2] = hi ? B0 : recv0;   // e4,e5 (from hi'=1 source)
            pw[3] = hi ? B1 : recv1;   // e6,e7
            bf16x8 pb = __builtin_bit_cast(bf16x8, pw);
#pragma unroll
            for (int dblk = 0; dblk < 2; ++dblk) {
                bf16x8 vf = *(const bf16x8*)(vb + (dblk * 32 + l31) * 128 + ((g * 32 + hi * 16) ^ swz));
                ot[dblk] = __builtin_amdgcn_mfma_f32_32x32x16_bf16(vf, pb, ot[dblk], 0, 0, 0);
            }
        }
        __builtin_amdgcn_s_setprio(0);
        __syncthreads();
        buf ^= 1;
    }

    // epilogue: lane holds O^T[d = 32*dblk + 8*m + 4*hi + (r&3)][q = lane&31]
    const int nb = b >> 4, h = b & 15;
    float inv = __builtin_amdgcn_rcpf(lsum);
    const size_t row = (size_t)qrow * 2 + nb;
#pragma unroll
    for (int dblk = 0; dblk < 2; ++dblk) {
#pragma unroll
        for (int m = 0; m < 4; ++m) {
            float a0 = ot[dblk][4 * m + 0] * inv, a1 = ot[dblk][4 * m + 1] * inv;
            float a2 = ot[dblk][4 * m + 2] * inv, a3 = ot[dblk][4 * m + 3] * inv;
            unsigned w0, w1;
            asm("v_cvt_pk_bf16_f32 %0, %1, %2" : "=v"(w0) : "v"(a0), "v"(a1));
            asm("v_cvt_pk_bf16_f32 %0, %1, %2" : "=v"(w1) : "v"(a2), "v"(a3));
            uint2 st; st.x = w0; st.y = w1;
            *(uint2*)(attn_out + row * 1024 + h * 64 + dblk * 32 + m * 8 + hi * 4) = st;
        }
    }
}

// ---------------- Output projection GEMM ----------------
__global__ __launch_bounds__(256, 3) void gemm_out(
    const ushort* __restrict__ A, const ushort* __restrict__ B,
    const float* __restrict__ bias, float* __restrict__ out)
{
    __shared__ ushort As[128][64];
    __shared__ ushort Bs[128][64];
    const int tid = threadIdx.x;
    const int lane = tid & 63, wave = tid >> 6;
    const int wr = (wave >> 1) * 64, wc = (wave & 1) * 64;
    const int lr = lane & 15, lg = lane >> 4;
    const int swz = (lr & 7) << 4;
    const int sl = lane >> 3;
    const int scol = ((lane & 7) ^ sl) * 8;
    const int rowBase = blockIdx.y * 128, colBase = blockIdx.x * 128;

    f32x4 acc[4][4] = {};
    for (int k0 = 0; k0 < 1024; k0 += 64) {
        __syncthreads();
        int s0 = wave * 4;
#pragma unroll
        for (int i = 0; i < 4; ++i) {
            int s = s0 + i;
            gld_lds16(A + (size_t)(rowBase + s * 8 + sl) * 1024 + k0 + scol, &As[s * 8][0]);
            gld_lds16(B + (size_t)(colBase + s * 8 + sl) * 1024 + k0 + scol, &Bs[s * 8][0]);
        }
        __syncthreads();
#pragma unroll
        for (int kk = 0; kk < 2; ++kk) {
            bf16x8 af[4], bfr[4];
#pragma unroll
            for (int m = 0; m < 4; ++m)
                af[m] = *(const bf16x8*)((const char*)As + (wr + m * 16 + lr) * 128 + ((kk * 64 + lg * 16) ^ swz));
#pragma unroll
            for (int n = 0; n < 4; ++n)
                bfr[n] = *(const bf16x8*)((const char*)Bs + (wc + n * 16 + lr) * 128 + ((kk * 64 + lg * 16) ^ swz));
#pragma unroll
            for (int m = 0; m < 4; ++m)
#pragma unroll
                for (int n = 0; n < 4; ++n)
                    acc[m][n] = __builtin_amdgcn_mfma_f32_16x16x32_bf16(af[m], bfr[n], acc[m][n], 0, 0, 0);
        }
    }
#pragma unroll
    for (int n = 0; n < 4; ++n) {
        int e = colBase + wc + n * 16 + lr;
        float bv = bias[e];
#pragma unroll
        for (int m = 0; m < 4; ++m) {
#pragma unroll
            for (int j = 0; j < 4; ++j) {
                int row = rowBase + wr + m * 16 + lg * 4 + j;
                out[(size_t)row * 1024 + e] = acc[m][n][j] + bv;
            }
        }
    }
}

extern "C" void kernel_launch(void* const* d_in, const int* in_sizes, int n_in,
                              void* d_out, int out_size, void* d_ws, size_t ws_size,
                              hipStream_t stream) {
    const float* query    = (const float*)d_in[0];
    const float* qkv_proj = (const float*)d_in[1];
    const float* qkv_bias = (const float*)d_in[2];
    const float* out_proj = (const float*)d_in[3];
    const float* out_bias = (const float*)d_in[4];
    float* out = (float*)d_out;

    char* ws = (char*)d_ws;
    ushort* qbf      = (ushort*)ws;                      // 8 MB  query bf16 [4096][1024]
    ushort* wqkv     = (ushort*)(ws + (8ull << 20));     // 6 MB  qkv_proj bf16 [3072][1024]
    ushort* wout     = (ushort*)(ws + (14ull << 20));    // 2 MB  out_proj bf16 [1024][1024]
    ushort* qh       = (ushort*)(ws + (16ull << 20));    // 8 MB  [32][2048][64] (pre-scaled by SCALE*LOG2E)
    ushort* kh       = (ushort*)(ws + (24ull << 20));    // 8 MB  [32][2048][64]
    ushort* vT       = (ushort*)(ws + (32ull << 20));    // 8 MB  [32][64][2048]
    ushort* attn_out = (ushort*)(ws + (40ull << 20));    // 8 MB  [4096][1024]

    cast_kernel<<<4096, 256, 0, stream>>>(query, qbf, 1048576);
    cast_kernel<<<3072, 256, 0, stream>>>(qkv_proj, wqkv, 786432);
    cast_kernel<<<1024, 256, 0, stream>>>(out_proj, wout, 262144);
    gemm_qkv<<<dim3(24, 32), 256, 0, stream>>>(qbf, wqkv, qkv_bias, qh, kh, vT);
    attn_kernel<<<dim3(16, 32), 256, 0, stream>>>(qh, kh, vT, attn_out);
    gemm_out<<<dim3(8, 32), 256, 0, stream>>>(attn_out, wout, out_bias, out);
}

// Round 5
// 143.331 us; speedup vs baseline: 1.4726x; 1.0126x over previous
//
#include <hip/hip_runtime.h>
#include <stdint.h>

#define SCALE 0.125f   // D^-0.5, D=64
#define LOG2E 1.44269504088896340736f
#define QK_SCALE (SCALE * LOG2E)   // S in log2 domain -> bare v_exp_f32

typedef __bf16 bf16x8 __attribute__((ext_vector_type(8)));
typedef float f32x4 __attribute__((ext_vector_type(4)));
typedef float f32x16 __attribute__((ext_vector_type(16)));
typedef unsigned u32x4 __attribute__((ext_vector_type(4)));

__device__ __forceinline__ ushort f2bf(float x) {
    union { float f; unsigned u; } v; v.f = x;
    unsigned r = v.u + 0x7FFFu + ((v.u >> 16) & 1u);  // RNE
    return (ushort)(r >> 16);
}

// async 16B global->LDS
__device__ __forceinline__ void gld_lds16(const void* g, void* l) {
    __builtin_amdgcn_global_load_lds(
        reinterpret_cast<const unsigned __attribute__((address_space(1)))*>(
            reinterpret_cast<uintptr_t>(g)),
        reinterpret_cast<unsigned __attribute__((address_space(3)))*>(
            (unsigned)reinterpret_cast<uintptr_t>(l)),
        16, 0, 0);
}

// ---------------- fused fp32 -> bf16 cast of all three operands ----------------
// segment 0: query 1048576 float4, segment 1: qkv_proj 786432, segment 2: out_proj 262144
__global__ __launch_bounds__(256) void cast_fused(const float* __restrict__ s0,
                                                  const float* __restrict__ s1,
                                                  const float* __restrict__ s2,
                                                  ushort* __restrict__ d0,
                                                  ushort* __restrict__ d1,
                                                  ushort* __restrict__ d2) {
    int i = blockIdx.x * 256 + threadIdx.x;
    const float* src; ushort* dst; int idx;
    if (i < 1048576)            { src = s0; dst = d0; idx = i; }
    else if (i < 1048576 + 786432) { src = s1; dst = d1; idx = i - 1048576; }
    else                        { src = s2; dst = d2; idx = i - (1048576 + 786432); }
    float4 v = ((const float4*)src)[idx];
    ushort4 o;
    o.x = f2bf(v.x); o.y = f2bf(v.y); o.z = f2bf(v.z); o.w = f2bf(v.w);
    ((ushort4*)dst)[idx] = o;
}

// ---------------- QKV projection GEMM ----------------
// Each block computes a 128x128 tile of ONE of q/k/v: which = blockIdx.x>>3,
// i0 = (blockIdx.x&7)*128. B rows staged with stride 3: f = 3*(i0+r)+which.
// Epilogue is branch-uniform per block, no div/mod.
__global__ __launch_bounds__(256, 3) void gemm_qkv(
    const ushort* __restrict__ A, const ushort* __restrict__ B,
    const float* __restrict__ bias,
    ushort* __restrict__ qh, ushort* __restrict__ kh, ushort* __restrict__ vT)
{
    __shared__ ushort As[128][64];
    __shared__ ushort Bs[128][64];
    const int tid = threadIdx.x;
    const int lane = tid & 63, wave = tid >> 6;
    const int wr = (wave >> 1) * 64, wc = (wave & 1) * 64;
    const int lr = lane & 15, lg = lane >> 4;
    const int swz = (lr & 7) << 4;
    const int sl = lane >> 3;
    const int scol = ((lane & 7) ^ sl) * 8;
    const int rowBase = blockIdx.y * 128;
    const int which = blockIdx.x >> 3;
    const int i0 = (blockIdx.x & 7) * 128;

    f32x4 acc[4][4] = {};
    for (int k0 = 0; k0 < 1024; k0 += 64) {
        __syncthreads();
        int s0 = wave * 4;
#pragma unroll
        for (int i = 0; i < 4; ++i) {
            int s = s0 + i;
            int r = s * 8 + sl;
            gld_lds16(A + (size_t)(rowBase + r) * 1024 + k0 + scol, &As[s * 8][0]);
            gld_lds16(B + (size_t)(3 * (i0 + r) + which) * 1024 + k0 + scol, &Bs[s * 8][0]);
        }
        __syncthreads();
#pragma unroll
        for (int kk = 0; kk < 2; ++kk) {
            bf16x8 af[4], bfr[4];
#pragma unroll
            for (int m = 0; m < 4; ++m)
                af[m] = *(const bf16x8*)((const char*)As + (wr + m * 16 + lr) * 128 + ((kk * 64 + lg * 16) ^ swz));
#pragma unroll
            for (int n = 0; n < 4; ++n)
                bfr[n] = *(const bf16x8*)((const char*)Bs + (wc + n * 16 + lr) * 128 + ((kk * 64 + lg * 16) ^ swz));
#pragma unroll
            for (int m = 0; m < 4; ++m)
#pragma unroll
                for (int n = 0; n < 4; ++n)
                    acc[m][n] = __builtin_amdgcn_mfma_f32_16x16x32_bf16(af[m], bfr[n], acc[m][n], 0, 0, 0);
        }
    }
#pragma unroll
    for (int n = 0; n < 4; ++n) {
        int i = i0 + wc + n * 16 + lr;
        float bv = bias[3 * i + which];
        int h = i >> 6, d = i & 63;
#pragma unroll
        for (int m = 0; m < 4; ++m) {
#pragma unroll
            for (int j = 0; j < 4; ++j) {
                int row = rowBase + wr + m * 16 + lg * 4 + j;
                int l = row >> 1, nb = row & 1;
                int bh = nb * 16 + h;
                float v = acc[m][n][j] + bv;
                if (which == 0)      qh[((size_t)bh * 2048 + l) * 64 + d] = f2bf(v * QK_SCALE);
                else if (which == 1) kh[((size_t)bh * 2048 + l) * 64 + d] = f2bf(v);
                else                 vT[((size_t)bh * 64 + d) * 2048 + l] = f2bf(v);
            }
        }
    }
}

// ---------------- Flash attention: 32x32 MFMA, 2-wave blocks for overlap ----------------
// Block: 2 waves x 32 q = 64 q-rows; grid (32, 32) -> 4 blocks/CU, staggered barrier domains.
// sc[blk] = mfma_32x32x16(K-frag, Q-frag): lane holds S^T[kv][q=lane&31],
//   kv = blk*32 + (r&3) + 8*(r>>2) + 4*hi  (r = reg 0..15, hi = lane>>5)
__global__ __launch_bounds__(128, 2) void attn_kernel(
    const ushort* __restrict__ qh, const ushort* __restrict__ kh,
    const ushort* __restrict__ vT, ushort* __restrict__ attn_out)
{
    __shared__ ushort Ks[2][64][64];
    __shared__ ushort Vs[2][64][64];   // V^T tile: [d][kv]
    const int tid = threadIdx.x, lane = tid & 63, wave = tid >> 6;
    const int l31 = lane & 31, hi = lane >> 5;
    const int swz = (lane & 7) << 4;   // row&7 == lane&7 for rows = blk*32 + l31
    const int b = blockIdx.y;
    const int qBase = blockIdx.x * 64;
    const int qrow = qBase + wave * 32 + l31;
    const int sl = lane >> 3;
    const int scol = ((lane & 7) ^ sl) * 8;
    const size_t kBase = (size_t)b * 2048;
    const size_t vBase = (size_t)b * 64;

    // Q B-fragments (col=q=lane&31, k = kk*16 + hi*8 + e), persistent
    bf16x8 qf[4];
#pragma unroll
    for (int kk = 0; kk < 4; ++kk)
        qf[kk] = *(const bf16x8*)(qh + (kBase + qrow) * 64 + kk * 16 + hi * 8);

    f32x16 ot[2] = {};
    float mrun = -1e30f, lsum = 0.f;

    // prologue: stage tile 0 into buf 0 (8 K-slabs + 8 V-slabs over 2 waves)
    {
        int s0 = wave * 4;
#pragma unroll
        for (int i = 0; i < 4; ++i) {
            int s = s0 + i;
            gld_lds16(kh + (kBase + s * 8 + sl) * 64 + scol, &Ks[0][s * 8][0]);
            gld_lds16(vT + (vBase + s * 8 + sl) * 2048 + scol, &Vs[0][s * 8][0]);
        }
    }
    __syncthreads();

    int buf = 0;
    for (int t = 0; t < 32; ++t) {
        if (t < 31) {
            int s0 = wave * 4;
#pragma unroll
            for (int i = 0; i < 4; ++i) {
                int s = s0 + i;
                gld_lds16(kh + (kBase + (t + 1) * 64 + s * 8 + sl) * 64 + scol, &Ks[buf ^ 1][s * 8][0]);
                gld_lds16(vT + (vBase + s * 8 + sl) * 2048 + (t + 1) * 64 + scol, &Vs[buf ^ 1][s * 8][0]);
            }
        }
        const char* kb = (const char*)Ks + buf * 8192;
        const char* vb = (const char*)Vs + buf * 8192;

        // S^T = K Q^T
        f32x16 sc[2] = {};
        __builtin_amdgcn_s_setprio(1);
#pragma unroll
        for (int blk = 0; blk < 2; ++blk) {
#pragma unroll
            for (int kk = 0; kk < 4; ++kk) {
                bf16x8 kf = *(const bf16x8*)(kb + (blk * 32 + l31) * 128 + ((kk * 32 + hi * 16) ^ swz));
                sc[blk] = __builtin_amdgcn_mfma_f32_32x32x16_bf16(kf, qf[kk], sc[blk], 0, 0, 0);
            }
        }
        __builtin_amdgcn_s_setprio(0);

        // lane-local row max over 32 values + cross-half combine (shfl_xor 32)
        float mx = sc[0][0];
#pragma unroll
        for (int blk = 0; blk < 2; ++blk)
#pragma unroll
            for (int r = 0; r < 16; ++r)
                mx = fmaxf(mx, sc[blk][r]);
        mx = fmaxf(mx, __shfl_xor(mx, 32));
        if (!__all(mx - mrun <= 8.0f)) {   // defer-max (T13)
            float mnew = fmaxf(mrun, mx);
            float alpha = __builtin_amdgcn_exp2f(mrun - mnew);
            mrun = mnew;
            lsum *= alpha;
#pragma unroll
            for (int blk = 0; blk < 2; ++blk)
#pragma unroll
                for (int r = 0; r < 16; ++r)
                    ot[blk][r] *= alpha;
        }
        float rs = 0.f;
#pragma unroll
        for (int blk = 0; blk < 2; ++blk)
#pragma unroll
            for (int r = 0; r < 16; ++r) {
                float p = __builtin_amdgcn_exp2f(sc[blk][r] - mrun);
                sc[blk][r] = p;
                rs += p;
            }
        rs += __shfl_xor(rs, 32);
        lsum += rs;

        // P -> B-frags + PV. Target lane (l31,hi), group g: pb[e] = P[q=l31][kv=g*16+hi*8+e].
        __builtin_amdgcn_s_setprio(1);
#pragma unroll
        for (int g = 0; g < 4; ++g) {
            const int blk = g >> 1;
            const int base = (g & 1) * 8;   // = 4*m0
            unsigned A0, A1, B0, B1;
            asm("v_cvt_pk_bf16_f32 %0, %1, %2" : "=v"(A0) : "v"(sc[blk][base + 0]), "v"(sc[blk][base + 1]));
            asm("v_cvt_pk_bf16_f32 %0, %1, %2" : "=v"(A1) : "v"(sc[blk][base + 2]), "v"(sc[blk][base + 3]));
            asm("v_cvt_pk_bf16_f32 %0, %1, %2" : "=v"(B0) : "v"(sc[blk][base + 4]), "v"(sc[blk][base + 5]));
            asm("v_cvt_pk_bf16_f32 %0, %1, %2" : "=v"(B1) : "v"(sc[blk][base + 6]), "v"(sc[blk][base + 7]));
            unsigned send0 = hi ? A0 : B0, send1 = hi ? A1 : B1;
            unsigned recv0 = (unsigned)__shfl_xor((int)send0, 32);
            unsigned recv1 = (unsigned)__shfl_xor((int)send1, 32);
            u32x4 pw;
            pw[0] = hi ? recv0 : A0;
            pw[1] = hi ? recv1 : A1;
            pw[2] = hi ? B0 : recv0;
            pw[3] = hi ? B1 : recv1;
            bf16x8 pb = __builtin_bit_cast(bf16x8, pw);
#pragma unroll
            for (int dblk = 0; dblk < 2; ++dblk) {
                bf16x8 vf = *(const bf16x8*)(vb + (dblk * 32 + l31) * 128 + ((g * 32 + hi * 16) ^ swz));
                ot[dblk] = __builtin_amdgcn_mfma_f32_32x32x16_bf16(vf, pb, ot[dblk], 0, 0, 0);
            }
        }
        __builtin_amdgcn_s_setprio(0);
        __syncthreads();
        buf ^= 1;
    }

    // epilogue: lane holds O^T[d = 32*dblk + 8*m + 4*hi + (r&3)][q = lane&31]
    const int nb = b >> 4, h = b & 15;
    float inv = __builtin_amdgcn_rcpf(lsum);
    const size_t row = (size_t)qrow * 2 + nb;
#pragma unroll
    for (int dblk = 0; dblk < 2; ++dblk) {
#pragma unroll
        for (int m = 0; m < 4; ++m) {
            float a0 = ot[dblk][4 * m + 0] * inv, a1 = ot[dblk][4 * m + 1] * inv;
            float a2 = ot[dblk][4 * m + 2] * inv, a3 = ot[dblk][4 * m + 3] * inv;
            unsigned w0, w1;
            asm("v_cvt_pk_bf16_f32 %0, %1, %2" : "=v"(w0) : "v"(a0), "v"(a1));
            asm("v_cvt_pk_bf16_f32 %0, %1, %2" : "=v"(w1) : "v"(a2), "v"(a3));
            uint2 st; st.x = w0; st.y = w1;
            *(uint2*)(attn_out + row * 1024 + h * 64 + dblk * 32 + m * 8 + hi * 4) = st;
        }
    }
}

// ---------------- Output projection GEMM ----------------
__global__ __launch_bounds__(256, 3) void gemm_out(
    const ushort* __restrict__ A, const ushort* __restrict__ B,
    const float* __restrict__ bias, float* __restrict__ out)
{
    __shared__ ushort As[128][64];
    __shared__ ushort Bs[128][64];
    const int tid = threadIdx.x;
    const int lane = tid & 63, wave = tid >> 6;
    const int wr = (wave >> 1) * 64, wc = (wave & 1) * 64;
    const int lr = lane & 15, lg = lane >> 4;
    const int swz = (lr & 7) << 4;
    const int sl = lane >> 3;
    const int scol = ((lane & 7) ^ sl) * 8;
    const int rowBase = blockIdx.y * 128, colBase = blockIdx.x * 128;

    f32x4 acc[4][4] = {};
    for (int k0 = 0; k0 < 1024; k0 += 64) {
        __syncthreads();
        int s0 = wave * 4;
#pragma unroll
        for (int i = 0; i < 4; ++i) {
            int s = s0 + i;
            gld_lds16(A + (size_t)(rowBase + s * 8 + sl) * 1024 + k0 + scol, &As[s * 8][0]);
            gld_lds16(B + (size_t)(colBase + s * 8 + sl) * 1024 + k0 + scol, &Bs[s * 8][0]);
        }
        __syncthreads();
#pragma unroll
        for (int kk = 0; kk < 2; ++kk) {
            bf16x8 af[4], bfr[4];
#pragma unroll
            for (int m = 0; m < 4; ++m)
                af[m] = *(const bf16x8*)((const char*)As + (wr + m * 16 + lr) * 128 + ((kk * 64 + lg * 16) ^ swz));
#pragma unroll
            for (int n = 0; n < 4; ++n)
                bfr[n] = *(const bf16x8*)((const char*)Bs + (wc + n * 16 + lr) * 128 + ((kk * 64 + lg * 16) ^ swz));
#pragma unroll
            for (int m = 0; m < 4; ++m)
#pragma unroll
                for (int n = 0; n < 4; ++n)
                    acc[m][n] = __builtin_amdgcn_mfma_f32_16x16x32_bf16(af[m], bfr[n], acc[m][n], 0, 0, 0);
        }
    }
#pragma unroll
    for (int n = 0; n < 4; ++n) {
        int e = colBase + wc + n * 16 + lr;
        float bv = bias[e];
#pragma unroll
        for (int m = 0; m < 4; ++m) {
#pragma unroll
            for (int j = 0; j < 4; ++j) {
                int row = rowBase + wr + m * 16 + lg * 4 + j;
                out[(size_t)row * 1024 + e] = acc[m][n][j] + bv;
            }
        }
    }
}

extern "C" void kernel_launch(void* const* d_in, const int* in_sizes, int n_in,
                              void* d_out, int out_size, void* d_ws, size_t ws_size,
                              hipStream_t stream) {
    const float* query    = (const float*)d_in[0];
    const float* qkv_proj = (const float*)d_in[1];
    const float* qkv_bias = (const float*)d_in[2];
    const float* out_proj = (const float*)d_in[3];
    const float* out_bias = (const float*)d_in[4];
    float* out = (float*)d_out;

    char* ws = (char*)d_ws;
    ushort* qbf      = (ushort*)ws;                      // 8 MB  query bf16 [4096][1024]
    ushort* wqkv     = (ushort*)(ws + (8ull << 20));     // 6 MB  qkv_proj bf16 [3072][1024]
    ushort* wout     = (ushort*)(ws + (14ull << 20));    // 2 MB  out_proj bf16 [1024][1024]
    ushort* qh       = (ushort*)(ws + (16ull << 20));    // 8 MB  [32][2048][64] (pre-scaled by SCALE*LOG2E)
    ushort* kh       = (ushort*)(ws + (24ull << 20));    // 8 MB  [32][2048][64]
    ushort* vT       = (ushort*)(ws + (32ull << 20));    // 8 MB  [32][64][2048]
    ushort* attn_out = (ushort*)(ws + (40ull << 20));    // 8 MB  [4096][1024]

    cast_fused<<<8192, 256, 0, stream>>>(query, qkv_proj, out_proj, qbf, wqkv, wout);
    gemm_qkv<<<dim3(24, 32), 256, 0, stream>>>(qbf, wqkv, qkv_bias, qh, kh, vT);
    attn_kernel<<<dim3(32, 32), 128, 0, stream>>>(qh, kh, vT, attn_out);
    gemm_out<<<dim3(8, 32), 256, 0, stream>>>(attn_out, wout, out_bias, out);
}

// Round 6
// 135.651 us; speedup vs baseline: 1.5559x; 1.0566x over previous
//
#include <hip/hip_runtime.h>
#include <stdint.h>

#define SCALE 0.125f   // D^-0.5, D=64
#define LOG2E 1.44269504088896340736f
#define QK_SCALE (SCALE * LOG2E)   // S in log2 domain -> bare v_exp_f32

typedef __bf16 bf16x8 __attribute__((ext_vector_type(8)));
typedef float f32x4 __attribute__((ext_vector_type(4)));
typedef float f32x16 __attribute__((ext_vector_type(16)));
typedef unsigned u32x4 __attribute__((ext_vector_type(4)));

__device__ __forceinline__ ushort f2bf(float x) {
    union { float f; unsigned u; } v; v.f = x;
    unsigned r = v.u + 0x7FFFu + ((v.u >> 16) & 1u);  // RNE
    return (ushort)(r >> 16);
}

// async 16B global->LDS
__device__ __forceinline__ void gld_lds16(const void* g, void* l) {
    __builtin_amdgcn_global_load_lds(
        reinterpret_cast<const unsigned __attribute__((address_space(1)))*>(
            reinterpret_cast<uintptr_t>(g)),
        reinterpret_cast<unsigned __attribute__((address_space(3)))*>(
            (unsigned)reinterpret_cast<uintptr_t>(l)),
        16, 0, 0);
}

// ---------------- fused fp32 -> bf16 cast of all three operands ----------------
__global__ __launch_bounds__(256) void cast_fused(const float* __restrict__ s0,
                                                  const float* __restrict__ s1,
                                                  const float* __restrict__ s2,
                                                  ushort* __restrict__ d0,
                                                  ushort* __restrict__ d1,
                                                  ushort* __restrict__ d2) {
    int i = blockIdx.x * 256 + threadIdx.x;
    const float* src; ushort* dst; int idx;
    if (i < 1048576)            { src = s0; dst = d0; idx = i; }
    else if (i < 1048576 + 786432) { src = s1; dst = d1; idx = i - 1048576; }
    else                        { src = s2; dst = d2; idx = i - (1048576 + 786432); }
    float4 v = ((const float4*)src)[idx];
    ushort4 o;
    o.x = f2bf(v.x); o.y = f2bf(v.y); o.z = f2bf(v.z); o.w = f2bf(v.w);
    ((ushort4*)dst)[idx] = o;
}

// ---------------- QKV projection GEMM (which-uniform blocks) ----------------
__global__ __launch_bounds__(256, 3) void gemm_qkv(
    const ushort* __restrict__ A, const ushort* __restrict__ B,
    const float* __restrict__ bias,
    ushort* __restrict__ qh, ushort* __restrict__ kh, ushort* __restrict__ vT)
{
    __shared__ ushort As[128][64];
    __shared__ ushort Bs[128][64];
    const int tid = threadIdx.x;
    const int lane = tid & 63, wave = tid >> 6;
    const int wr = (wave >> 1) * 64, wc = (wave & 1) * 64;
    const int lr = lane & 15, lg = lane >> 4;
    const int swz = (lr & 7) << 4;
    const int sl = lane >> 3;
    const int scol = ((lane & 7) ^ sl) * 8;
    const int rowBase = blockIdx.y * 128;
    const int which = blockIdx.x >> 3;
    const int i0 = (blockIdx.x & 7) * 128;

    f32x4 acc[4][4] = {};
    for (int k0 = 0; k0 < 1024; k0 += 64) {
        __syncthreads();
        int s0 = wave * 4;
#pragma unroll
        for (int i = 0; i < 4; ++i) {
            int s = s0 + i;
            int r = s * 8 + sl;
            gld_lds16(A + (size_t)(rowBase + r) * 1024 + k0 + scol, &As[s * 8][0]);
            gld_lds16(B + (size_t)(3 * (i0 + r) + which) * 1024 + k0 + scol, &Bs[s * 8][0]);
        }
        __syncthreads();
#pragma unroll
        for (int kk = 0; kk < 2; ++kk) {
            bf16x8 af[4], bfr[4];
#pragma unroll
            for (int m = 0; m < 4; ++m)
                af[m] = *(const bf16x8*)((const char*)As + (wr + m * 16 + lr) * 128 + ((kk * 64 + lg * 16) ^ swz));
#pragma unroll
            for (int n = 0; n < 4; ++n)
                bfr[n] = *(const bf16x8*)((const char*)Bs + (wc + n * 16 + lr) * 128 + ((kk * 64 + lg * 16) ^ swz));
#pragma unroll
            for (int m = 0; m < 4; ++m)
#pragma unroll
                for (int n = 0; n < 4; ++n)
                    acc[m][n] = __builtin_amdgcn_mfma_f32_16x16x32_bf16(af[m], bfr[n], acc[m][n], 0, 0, 0);
        }
    }
#pragma unroll
    for (int n = 0; n < 4; ++n) {
        int i = i0 + wc + n * 16 + lr;
        float bv = bias[3 * i + which];
        int h = i >> 6, d = i & 63;
#pragma unroll
        for (int m = 0; m < 4; ++m) {
#pragma unroll
            for (int j = 0; j < 4; ++j) {
                int row = rowBase + wr + m * 16 + lg * 4 + j;
                int l = row >> 1, nb = row & 1;
                int bh = nb * 16 + h;
                float v = acc[m][n][j] + bv;
                if (which == 0)      qh[((size_t)bh * 2048 + l) * 64 + d] = f2bf(v * QK_SCALE);
                else if (which == 1) kh[((size_t)bh * 2048 + l) * 64 + d] = f2bf(v);
                else                 vT[((size_t)bh * 64 + d) * 2048 + l] = f2bf(v);
            }
        }
    }
}

// ---------------- Flash attention: 32x32 MFMA, 4 waves, optional split-KV ----------------
// Block: 4 waves x 32 q = 128 q-rows; blockIdx.z selects KV half (ntiles tiles each).
// split=1: write unnormalized O (f32) + (m, l) partials; split=0: normalize and store bf16.
__global__ __launch_bounds__(256, 4) void attn_kernel(
    const ushort* __restrict__ qh, const ushort* __restrict__ kh,
    const ushort* __restrict__ vT, ushort* __restrict__ attn_out,
    float* __restrict__ opart, float* __restrict__ ml,
    int ntiles, int split)
{
    __shared__ ushort Ks[2][64][64];
    __shared__ ushort Vs[2][64][64];   // V^T tile: [d][kv]
    const int tid = threadIdx.x, lane = tid & 63, wave = tid >> 6;
    const int l31 = lane & 31, hi = lane >> 5;
    const int swz = (lane & 7) << 4;   // row&7 == lane&7 for rows = blk*32 + l31
    const int b = blockIdx.y;
    const int qBase = blockIdx.x * 128;
    const int qrow = qBase + wave * 32 + l31;
    const int sl = lane >> 3;
    const int scol = ((lane & 7) ^ sl) * 8;
    const size_t kBase = (size_t)b * 2048;
    const size_t vBase = (size_t)b * 64;
    const int t0 = blockIdx.z * ntiles, t1 = t0 + ntiles;

    // Q B-fragments (col=q=lane&31, k = kk*16 + hi*8 + e), persistent
    bf16x8 qf[4];
#pragma unroll
    for (int kk = 0; kk < 4; ++kk)
        qf[kk] = *(const bf16x8*)(qh + (kBase + qrow) * 64 + kk * 16 + hi * 8);

    f32x16 ot[2] = {};
    float mrun = -1e30f, lsum = 0.f;

    // prologue: stage tile t0 into buf 0
    {
        int s0 = wave * 2;
#pragma unroll
        for (int i = 0; i < 2; ++i) {
            int s = s0 + i;
            gld_lds16(kh + (kBase + t0 * 64 + s * 8 + sl) * 64 + scol, &Ks[0][s * 8][0]);
            gld_lds16(vT + (vBase + s * 8 + sl) * 2048 + t0 * 64 + scol, &Vs[0][s * 8][0]);
        }
    }
    __syncthreads();

    int buf = 0;
    for (int t = t0; t < t1; ++t) {
        if (t + 1 < t1) {
            int s0 = wave * 2;
#pragma unroll
            for (int i = 0; i < 2; ++i) {
                int s = s0 + i;
                gld_lds16(kh + (kBase + (t + 1) * 64 + s * 8 + sl) * 64 + scol, &Ks[buf ^ 1][s * 8][0]);
                gld_lds16(vT + (vBase + s * 8 + sl) * 2048 + (t + 1) * 64 + scol, &Vs[buf ^ 1][s * 8][0]);
            }
        }
        const char* kb = (const char*)Ks + buf * 8192;
        const char* vb = (const char*)Vs + buf * 8192;

        // S^T = K Q^T : lane holds S^T[kv][q=l31], kv = blk*32 + (r&3) + 8*(r>>2) + 4*hi
        f32x16 sc[2] = {};
        __builtin_amdgcn_s_setprio(1);
#pragma unroll
        for (int blk = 0; blk < 2; ++blk) {
#pragma unroll
            for (int kk = 0; kk < 4; ++kk) {
                bf16x8 kf = *(const bf16x8*)(kb + (blk * 32 + l31) * 128 + ((kk * 32 + hi * 16) ^ swz));
                sc[blk] = __builtin_amdgcn_mfma_f32_32x32x16_bf16(kf, qf[kk], sc[blk], 0, 0, 0);
            }
        }
        __builtin_amdgcn_s_setprio(0);

        // lane-local row max over 32 values + cross-half combine (shfl_xor 32)
        float mx = sc[0][0];
#pragma unroll
        for (int blk = 0; blk < 2; ++blk)
#pragma unroll
            for (int r = 0; r < 16; ++r)
                mx = fmaxf(mx, sc[blk][r]);
        mx = fmaxf(mx, __shfl_xor(mx, 32));
        if (!__all(mx - mrun <= 8.0f)) {   // defer-max (T13)
            float mnew = fmaxf(mrun, mx);
            float alpha = __builtin_amdgcn_exp2f(mrun - mnew);
            mrun = mnew;
            lsum *= alpha;
#pragma unroll
            for (int blk = 0; blk < 2; ++blk)
#pragma unroll
                for (int r = 0; r < 16; ++r)
                    ot[blk][r] *= alpha;
        }
        float rs = 0.f;
#pragma unroll
        for (int blk = 0; blk < 2; ++blk)
#pragma unroll
            for (int r = 0; r < 16; ++r) {
                float p = __builtin_amdgcn_exp2f(sc[blk][r] - mrun);
                sc[blk][r] = p;
                rs += p;
            }
        rs += __shfl_xor(rs, 32);
        lsum += rs;

        // P -> B-frags + PV. Target lane (l31,hi), group g: pb[e] = P[q=l31][kv=g*16+hi*8+e].
        __builtin_amdgcn_s_setprio(1);
#pragma unroll
        for (int g = 0; g < 4; ++g) {
            const int blk = g >> 1;
            const int base = (g & 1) * 8;
            unsigned A0, A1, B0, B1;
            asm("v_cvt_pk_bf16_f32 %0, %1, %2" : "=v"(A0) : "v"(sc[blk][base + 0]), "v"(sc[blk][base + 1]));
            asm("v_cvt_pk_bf16_f32 %0, %1, %2" : "=v"(A1) : "v"(sc[blk][base + 2]), "v"(sc[blk][base + 3]));
            asm("v_cvt_pk_bf16_f32 %0, %1, %2" : "=v"(B0) : "v"(sc[blk][base + 4]), "v"(sc[blk][base + 5]));
            asm("v_cvt_pk_bf16_f32 %0, %1, %2" : "=v"(B1) : "v"(sc[blk][base + 6]), "v"(sc[blk][base + 7]));
            unsigned send0 = hi ? A0 : B0, send1 = hi ? A1 : B1;
            unsigned recv0 = (unsigned)__shfl_xor((int)send0, 32);
            unsigned recv1 = (unsigned)__shfl_xor((int)send1, 32);
            u32x4 pw;
            pw[0] = hi ? recv0 : A0;
            pw[1] = hi ? recv1 : A1;
            pw[2] = hi ? B0 : recv0;
            pw[3] = hi ? B1 : recv1;
            bf16x8 pb = __builtin_bit_cast(bf16x8, pw);
#pragma unroll
            for (int dblk = 0; dblk < 2; ++dblk) {
                bf16x8 vf = *(const bf16x8*)(vb + (dblk * 32 + l31) * 128 + ((g * 32 + hi * 16) ^ swz));
                ot[dblk] = __builtin_amdgcn_mfma_f32_32x32x16_bf16(vf, pb, ot[dblk], 0, 0, 0);
            }
        }
        __builtin_amdgcn_s_setprio(0);
        __syncthreads();
        buf ^= 1;
    }

    // epilogue: lane holds O^T[d = 32*dblk + 8*m + 4*hi + (r&3)][q = lane&31]
    if (split) {
        // unnormalized partials: opart[z][b][qrow][d] f32, ml[z][b][qrow] = (m, l)
        float* op = opart + (((size_t)blockIdx.z * 32 + b) * 2048 + qrow) * 64;
#pragma unroll
        for (int dblk = 0; dblk < 2; ++dblk) {
#pragma unroll
            for (int m = 0; m < 4; ++m) {
                float4 st;
                st.x = ot[dblk][4 * m + 0]; st.y = ot[dblk][4 * m + 1];
                st.z = ot[dblk][4 * m + 2]; st.w = ot[dblk][4 * m + 3];
                *(float4*)(op + dblk * 32 + m * 8 + hi * 4) = st;
            }
        }
        if (!hi) {
            float2 v; v.x = mrun; v.y = lsum;
            ((float2*)ml)[((size_t)blockIdx.z * 32 + b) * 2048 + qrow] = v;
        }
    } else {
        const int nb = b >> 4, h = b & 15;
        float inv = __builtin_amdgcn_rcpf(lsum);
        const size_t row = (size_t)qrow * 2 + nb;
#pragma unroll
        for (int dblk = 0; dblk < 2; ++dblk) {
#pragma unroll
            for (int m = 0; m < 4; ++m) {
                float a0 = ot[dblk][4 * m + 0] * inv, a1 = ot[dblk][4 * m + 1] * inv;
                float a2 = ot[dblk][4 * m + 2] * inv, a3 = ot[dblk][4 * m + 3] * inv;
                unsigned w0, w1;
                asm("v_cvt_pk_bf16_f32 %0, %1, %2" : "=v"(w0) : "v"(a0), "v"(a1));
                asm("v_cvt_pk_bf16_f32 %0, %1, %2" : "=v"(w1) : "v"(a2), "v"(a3));
                uint2 st; st.x = w0; st.y = w1;
                *(uint2*)(attn_out + row * 1024 + h * 64 + dblk * 32 + m * 8 + hi * 4) = st;
            }
        }
    }
}

// ---------------- split-KV merge: combine 2 partials, normalize, pack bf16 ----------------
// idx -> (bh, q, c): c = d/4 in [0,16), 1,048,576 threads total
__global__ __launch_bounds__(256) void attn_merge(const float* __restrict__ opart,
                                                  const float* __restrict__ ml,
                                                  ushort* __restrict__ attn_out) {
    int idx = blockIdx.x * 256 + threadIdx.x;
    int c = idx & 15;
    int q = (idx >> 4) & 2047;
    int bh = idx >> 15;
    size_t base = (size_t)bh * 2048 + q;
    const size_t half = (size_t)32 * 2048;
    float2 ml0 = ((const float2*)ml)[base];
    float2 ml1 = ((const float2*)ml)[base + half];
    float m = fmaxf(ml0.x, ml1.x);
    float w0 = __builtin_amdgcn_exp2f(ml0.x - m);
    float w1 = __builtin_amdgcn_exp2f(ml1.x - m);
    float inv = __builtin_amdgcn_rcpf(ml0.y * w0 + ml1.y * w1);
    float4 o0 = ((const float4*)(opart + base * 64))[c];
    float4 o1 = ((const float4*)(opart + (base + half) * 64))[c];
    ushort4 r;
    r.x = f2bf((o0.x * w0 + o1.x * w1) * inv);
    r.y = f2bf((o0.y * w0 + o1.y * w1) * inv);
    r.z = f2bf((o0.z * w0 + o1.z * w1) * inv);
    r.w = f2bf((o0.w * w0 + o1.w * w1) * inv);
    int nb = bh >> 4, h = bh & 15;
    *(ushort4*)(attn_out + ((size_t)q * 2 + nb) * 1024 + h * 64 + c * 4) = r;
}

// ---------------- Output projection GEMM ----------------
__global__ __launch_bounds__(256, 3) void gemm_out(
    const ushort* __restrict__ A, const ushort* __restrict__ B,
    const float* __restrict__ bias, float* __restrict__ out)
{
    __shared__ ushort As[128][64];
    __shared__ ushort Bs[128][64];
    const int tid = threadIdx.x;
    const int lane = tid & 63, wave = tid >> 6;
    const int wr = (wave >> 1) * 64, wc = (wave & 1) * 64;
    const int lr = lane & 15, lg = lane >> 4;
    const int swz = (lr & 7) << 4;
    const int sl = lane >> 3;
    const int scol = ((lane & 7) ^ sl) * 8;
    const int rowBase = blockIdx.y * 128, colBase = blockIdx.x * 128;

    f32x4 acc[4][4] = {};
    for (int k0 = 0; k0 < 1024; k0 += 64) {
        __syncthreads();
        int s0 = wave * 4;
#pragma unroll
        for (int i = 0; i < 4; ++i) {
            int s = s0 + i;
            gld_lds16(A + (size_t)(rowBase + s * 8 + sl) * 1024 + k0 + scol, &As[s * 8][0]);
            gld_lds16(B + (size_t)(colBase + s * 8 + sl) * 1024 + k0 + scol, &Bs[s * 8][0]);
        }
        __syncthreads();
#pragma unroll
        for (int kk = 0; kk < 2; ++kk) {
            bf16x8 af[4], bfr[4];
#pragma unroll
            for (int m = 0; m < 4; ++m)
                af[m] = *(const bf16x8*)((const char*)As + (wr + m * 16 + lr) * 128 + ((kk * 64 + lg * 16) ^ swz));
#pragma unroll
            for (int n = 0; n < 4; ++n)
                bfr[n] = *(const bf16x8*)((const char*)Bs + (wc + n * 16 + lr) * 128 + ((kk * 64 + lg * 16) ^ swz));
#pragma unroll
            for (int m = 0; m < 4; ++m)
#pragma unroll
                for (int n = 0; n < 4; ++n)
                    acc[m][n] = __builtin_amdgcn_mfma_f32_16x16x32_bf16(af[m], bfr[n], acc[m][n], 0, 0, 0);
        }
    }
#pragma unroll
    for (int n = 0; n < 4; ++n) {
        int e = colBase + wc + n * 16 + lr;
        float bv = bias[e];
#pragma unroll
        for (int m = 0; m < 4; ++m) {
#pragma unroll
            for (int j = 0; j < 4; ++j) {
                int row = rowBase + wr + m * 16 + lg * 4 + j;
                out[(size_t)row * 1024 + e] = acc[m][n][j] + bv;
            }
        }
    }
}

extern "C" void kernel_launch(void* const* d_in, const int* in_sizes, int n_in,
                              void* d_out, int out_size, void* d_ws, size_t ws_size,
                              hipStream_t stream) {
    const float* query    = (const float*)d_in[0];
    const float* qkv_proj = (const float*)d_in[1];
    const float* qkv_bias = (const float*)d_in[2];
    const float* out_proj = (const float*)d_in[3];
    const float* out_bias = (const float*)d_in[4];
    float* out = (float*)d_out;

    char* ws = (char*)d_ws;
    ushort* qbf      = (ushort*)ws;                      // 8 MB  query bf16 [4096][1024]
    ushort* wqkv     = (ushort*)(ws + (8ull << 20));     // 6 MB  qkv_proj bf16 [3072][1024]
    ushort* wout     = (ushort*)(ws + (14ull << 20));    // 2 MB  out_proj bf16 [1024][1024]
    ushort* qh       = (ushort*)(ws + (16ull << 20));    // 8 MB  [32][2048][64] (pre-scaled by SCALE*LOG2E)
    ushort* kh       = (ushort*)(ws + (24ull << 20));    // 8 MB  [32][2048][64]
    ushort* vT       = (ushort*)(ws + (32ull << 20));    // 8 MB  [32][64][2048]
    ushort* attn_out = (ushort*)(ws + (40ull << 20));    // 8 MB  [4096][1024]
    float*  opart    = (float*)(ws + (48ull << 20));     // 34 MB [2][32][2048][64] f32
    float*  mlbuf    = (float*)(ws + (82ull << 20));     // 1 MB  [2][32][2048]{m,l}

    const bool split = ws_size >= (84ull << 20);

    cast_fused<<<8192, 256, 0, stream>>>(query, qkv_proj, out_proj, qbf, wqkv, wout);
    gemm_qkv<<<dim3(24, 32), 256, 0, stream>>>(qbf, wqkv, qkv_bias, qh, kh, vT);
    if (split) {
        attn_kernel<<<dim3(16, 32, 2), 256, 0, stream>>>(qh, kh, vT, attn_out, opart, mlbuf, 16, 1);
        attn_merge<<<4096, 256, 0, stream>>>(opart, mlbuf, attn_out);
    } else {
        attn_kernel<<<dim3(16, 32, 1), 256, 0, stream>>>(qh, kh, vT, attn_out, opart, mlbuf, 32, 0);
    }
    gemm_out<<<dim3(8, 32), 256, 0, stream>>>(attn_out, wout, out_bias, out);
}

// Round 7
// 128.840 us; speedup vs baseline: 1.6382x; 1.0529x over previous
//
#include <hip/hip_runtime.h>
#include <stdint.h>

#define SCALE 0.125f   // D^-0.5, D=64
#define LOG2E 1.44269504088896340736f
#define QK_SCALE (SCALE * LOG2E)   // S in log2 domain -> bare v_exp_f32

typedef __bf16 bf16x8 __attribute__((ext_vector_type(8)));
typedef float f32x4 __attribute__((ext_vector_type(4)));
typedef float f32x16 __attribute__((ext_vector_type(16)));
typedef unsigned u32x4 __attribute__((ext_vector_type(4)));

__device__ __forceinline__ ushort f2bf(float x) {
    union { float f; unsigned u; } v; v.f = x;
    unsigned r = v.u + 0x7FFFu + ((v.u >> 16) & 1u);  // RNE
    return (ushort)(r >> 16);
}

// async 16B global->LDS
__device__ __forceinline__ void gld_lds16(const void* g, void* l) {
    __builtin_amdgcn_global_load_lds(
        reinterpret_cast<const unsigned __attribute__((address_space(1)))*>(
            reinterpret_cast<uintptr_t>(g)),
        reinterpret_cast<unsigned __attribute__((address_space(3)))*>(
            (unsigned)reinterpret_cast<uintptr_t>(l)),
        16, 0, 0);
}

// ---------------- fused fp32 -> bf16 cast of all three operands ----------------
__global__ __launch_bounds__(256) void cast_fused(const float* __restrict__ s0,
                                                  const float* __restrict__ s1,
                                                  const float* __restrict__ s2,
                                                  ushort* __restrict__ d0,
                                                  ushort* __restrict__ d1,
                                                  ushort* __restrict__ d2) {
    int i = blockIdx.x * 256 + threadIdx.x;
    const float* src; ushort* dst; int idx;
    if (i < 1048576)            { src = s0; dst = d0; idx = i; }
    else if (i < 1048576 + 786432) { src = s1; dst = d1; idx = i - 1048576; }
    else                        { src = s2; dst = d2; idx = i - (1048576 + 786432); }
    float4 v = ((const float4*)src)[idx];
    ushort4 o;
    o.x = f2bf(v.x); o.y = f2bf(v.y); o.z = f2bf(v.z); o.w = f2bf(v.w);
    ((ushort4*)dst)[idx] = o;
}

// ---------------- QKV projection GEMM (which-uniform blocks) ----------------
// vT is stored with sequence index bit2<->bit3 swapped within each 64-block
// (sigma involution) so attention's PV B-fragment needs no cross-lane exchange.
__global__ __launch_bounds__(256, 3) void gemm_qkv(
    const ushort* __restrict__ A, const ushort* __restrict__ B,
    const float* __restrict__ bias,
    ushort* __restrict__ qh, ushort* __restrict__ kh, ushort* __restrict__ vT)
{
    __shared__ ushort As[128][64];
    __shared__ ushort Bs[128][64];
    const int tid = threadIdx.x;
    const int lane = tid & 63, wave = tid >> 6;
    const int wr = (wave >> 1) * 64, wc = (wave & 1) * 64;
    const int lr = lane & 15, lg = lane >> 4;
    const int swz = (lr & 7) << 4;
    const int sl = lane >> 3;
    const int scol = ((lane & 7) ^ sl) * 8;
    const int rowBase = blockIdx.y * 128;
    const int which = blockIdx.x >> 3;
    const int i0 = (blockIdx.x & 7) * 128;

    f32x4 acc[4][4] = {};
    for (int k0 = 0; k0 < 1024; k0 += 64) {
        __syncthreads();
        int s0 = wave * 4;
#pragma unroll
        for (int i = 0; i < 4; ++i) {
            int s = s0 + i;
            int r = s * 8 + sl;
            gld_lds16(A + (size_t)(rowBase + r) * 1024 + k0 + scol, &As[s * 8][0]);
            gld_lds16(B + (size_t)(3 * (i0 + r) + which) * 1024 + k0 + scol, &Bs[s * 8][0]);
        }
        __syncthreads();
#pragma unroll
        for (int kk = 0; kk < 2; ++kk) {
            bf16x8 af[4], bfr[4];
#pragma unroll
            for (int m = 0; m < 4; ++m)
                af[m] = *(const bf16x8*)((const char*)As + (wr + m * 16 + lr) * 128 + ((kk * 64 + lg * 16) ^ swz));
#pragma unroll
            for (int n = 0; n < 4; ++n)
                bfr[n] = *(const bf16x8*)((const char*)Bs + (wc + n * 16 + lr) * 128 + ((kk * 64 + lg * 16) ^ swz));
#pragma unroll
            for (int m = 0; m < 4; ++m)
#pragma unroll
                for (int n = 0; n < 4; ++n)
                    acc[m][n] = __builtin_amdgcn_mfma_f32_16x16x32_bf16(af[m], bfr[n], acc[m][n], 0, 0, 0);
        }
    }
#pragma unroll
    for (int n = 0; n < 4; ++n) {
        int i = i0 + wc + n * 16 + lr;
        float bv = bias[3 * i + which];
        int h = i >> 6, d = i & 63;
#pragma unroll
        for (int m = 0; m < 4; ++m) {
#pragma unroll
            for (int j = 0; j < 4; ++j) {
                int row = rowBase + wr + m * 16 + lg * 4 + j;
                int l = row >> 1, nb = row & 1;
                int bh = nb * 16 + h;
                float v = acc[m][n][j] + bv;
                if (which == 0)      qh[((size_t)bh * 2048 + l) * 64 + d] = f2bf(v * QK_SCALE);
                else if (which == 1) kh[((size_t)bh * 2048 + l) * 64 + d] = f2bf(v);
                else {
                    int lp = (l & ~12) | ((l & 4) << 1) | ((l & 8) >> 1);  // sigma: swap bits 2,3
                    vT[((size_t)bh * 64 + d) * 2048 + lp] = f2bf(v);
                }
            }
        }
    }
}

// ---------------- Flash attention: 32x32 MFMA, lane-local softmax, no P-exchange ----------------
// Block: 4 waves x 32 q = 128 q-rows; grid (16, 32). KV tiles of 64, double-buffered.
// sc[blk] = mfma_32x32x16(K-frag, Q-frag): lane holds S^T[kv][q=lane&31],
//   kv = blk*32 + (r&3) + 8*(r>>2) + 4*hi  (r = reg 0..15, hi = lane>>5)
// V^T stored sigma-permuted => PV B-frag pb[e] = sc[g>>1][8*(g&1)+e] (lane-local).
__global__ __launch_bounds__(256, 4) void attn_kernel(
    const ushort* __restrict__ qh, const ushort* __restrict__ kh,
    const ushort* __restrict__ vT, ushort* __restrict__ attn_out)
{
    __shared__ ushort Ks[2][64][64];
    __shared__ ushort Vs[2][64][64];   // sigma-permuted V^T tile: [d][kv']
    const int tid = threadIdx.x, lane = tid & 63, wave = tid >> 6;
    const int l31 = lane & 31, hi = lane >> 5;
    const int swz = (lane & 7) << 4;
    const int b = blockIdx.y;
    const int qBase = blockIdx.x * 128;
    const int qrow = qBase + wave * 32 + l31;
    const int sl = lane >> 3;
    const int scol = ((lane & 7) ^ sl) * 8;
    const size_t kBase = (size_t)b * 2048;
    const size_t vBase = (size_t)b * 64;

    // Q B-fragments (col=q=lane&31, k = kk*16 + hi*8 + e), persistent
    bf16x8 qf[4];
#pragma unroll
    for (int kk = 0; kk < 4; ++kk)
        qf[kk] = *(const bf16x8*)(qh + (kBase + qrow) * 64 + kk * 16 + hi * 8);

    f32x16 ot[2] = {};
    float mrun = -1e30f, lsum = 0.f;

    // prologue: stage tile 0 into buf 0
    {
        int s0 = wave * 2;
#pragma unroll
        for (int i = 0; i < 2; ++i) {
            int s = s0 + i;
            gld_lds16(kh + (kBase + s * 8 + sl) * 64 + scol, &Ks[0][s * 8][0]);
            gld_lds16(vT + (vBase + s * 8 + sl) * 2048 + scol, &Vs[0][s * 8][0]);
        }
    }
    __syncthreads();

    int buf = 0;
    for (int t = 0; t < 32; ++t) {
        if (t < 31) {
            int s0 = wave * 2;
#pragma unroll
            for (int i = 0; i < 2; ++i) {
                int s = s0 + i;
                gld_lds16(kh + (kBase + (t + 1) * 64 + s * 8 + sl) * 64 + scol, &Ks[buf ^ 1][s * 8][0]);
                gld_lds16(vT + (vBase + s * 8 + sl) * 2048 + (t + 1) * 64 + scol, &Vs[buf ^ 1][s * 8][0]);
            }
        }
        const char* kb = (const char*)Ks + buf * 8192;
        const char* vb = (const char*)Vs + buf * 8192;

        // S^T = K Q^T
        f32x16 sc[2] = {};
        __builtin_amdgcn_s_setprio(1);
#pragma unroll
        for (int blk = 0; blk < 2; ++blk) {
#pragma unroll
            for (int kk = 0; kk < 4; ++kk) {
                bf16x8 kf = *(const bf16x8*)(kb + (blk * 32 + l31) * 128 + ((kk * 32 + hi * 16) ^ swz));
                sc[blk] = __builtin_amdgcn_mfma_f32_32x32x16_bf16(kf, qf[kk], sc[blk], 0, 0, 0);
            }
        }
        __builtin_amdgcn_s_setprio(0);

        // row max: depth-5 tree + cross-half combine
        float tm[8];
#pragma unroll
        for (int i = 0; i < 8; ++i)
            tm[i] = fmaxf(fmaxf(sc[0][i], sc[0][i + 8]), fmaxf(sc[1][i], sc[1][i + 8]));
#pragma unroll
        for (int i = 0; i < 4; ++i)
            tm[i] = fmaxf(tm[i], tm[i + 4]);
        float mx = fmaxf(fmaxf(tm[0], tm[2]), fmaxf(tm[1], tm[3]));
        mx = fmaxf(mx, __shfl_xor(mx, 32));
        if (!__all(mx - mrun <= 8.0f)) {   // defer-max (T13)
            float mnew = fmaxf(mrun, mx);
            float alpha = __builtin_amdgcn_exp2f(mrun - mnew);
            mrun = mnew;
            lsum *= alpha;
#pragma unroll
            for (int blk = 0; blk < 2; ++blk)
#pragma unroll
                for (int r = 0; r < 16; ++r)
                    ot[blk][r] *= alpha;
        }
#pragma unroll
        for (int blk = 0; blk < 2; ++blk)
#pragma unroll
            for (int r = 0; r < 16; ++r)
                sc[blk][r] = __builtin_amdgcn_exp2f(sc[blk][r] - mrun);
        // row sum: depth-5 tree + cross-half combine
        float ts[8];
#pragma unroll
        for (int i = 0; i < 8; ++i)
            ts[i] = (sc[0][i] + sc[0][i + 8]) + (sc[1][i] + sc[1][i + 8]);
#pragma unroll
        for (int i = 0; i < 4; ++i)
            ts[i] += ts[i + 4];
        float rs = (ts[0] + ts[2]) + (ts[1] + ts[3]);
        rs += __shfl_xor(rs, 32);
        lsum += rs;

        // PV: pb[e] = sc[g>>1][8*(g&1)+e] (lane-local, sigma-permuted V)
        __builtin_amdgcn_s_setprio(1);
#pragma unroll
        for (int g = 0; g < 4; ++g) {
            const int blk = g >> 1;
            const int base = (g & 1) * 8;
            unsigned A0, A1, B0, B1;
            asm("v_cvt_pk_bf16_f32 %0, %1, %2" : "=v"(A0) : "v"(sc[blk][base + 0]), "v"(sc[blk][base + 1]));
            asm("v_cvt_pk_bf16_f32 %0, %1, %2" : "=v"(A1) : "v"(sc[blk][base + 2]), "v"(sc[blk][base + 3]));
            asm("v_cvt_pk_bf16_f32 %0, %1, %2" : "=v"(B0) : "v"(sc[blk][base + 4]), "v"(sc[blk][base + 5]));
            asm("v_cvt_pk_bf16_f32 %0, %1, %2" : "=v"(B1) : "v"(sc[blk][base + 6]), "v"(sc[blk][base + 7]));
            u32x4 pw; pw[0] = A0; pw[1] = A1; pw[2] = B0; pw[3] = B1;
            bf16x8 pb = __builtin_bit_cast(bf16x8, pw);
#pragma unroll
            for (int dblk = 0; dblk < 2; ++dblk) {
                bf16x8 vf = *(const bf16x8*)(vb + (dblk * 32 + l31) * 128 + ((g * 32 + hi * 16) ^ swz));
                ot[dblk] = __builtin_amdgcn_mfma_f32_32x32x16_bf16(vf, pb, ot[dblk], 0, 0, 0);
            }
        }
        __builtin_amdgcn_s_setprio(0);
        __syncthreads();
        buf ^= 1;
    }

    // epilogue: lane holds O^T[d = 32*dblk + 8*m + 4*hi + (r&3)][q = lane&31]
    const int nb = b >> 4, h = b & 15;
    float inv = __builtin_amdgcn_rcpf(lsum);
    const size_t row = (size_t)qrow * 2 + nb;
#pragma unroll
    for (int dblk = 0; dblk < 2; ++dblk) {
#pragma unroll
        for (int m = 0; m < 4; ++m) {
            float a0 = ot[dblk][4 * m + 0] * inv, a1 = ot[dblk][4 * m + 1] * inv;
            float a2 = ot[dblk][4 * m + 2] * inv, a3 = ot[dblk][4 * m + 3] * inv;
            unsigned w0, w1;
            asm("v_cvt_pk_bf16_f32 %0, %1, %2" : "=v"(w0) : "v"(a0), "v"(a1));
            asm("v_cvt_pk_bf16_f32 %0, %1, %2" : "=v"(w1) : "v"(a2), "v"(a3));
            uint2 st; st.x = w0; st.y = w1;
            *(uint2*)(attn_out + row * 1024 + h * 64 + dblk * 32 + m * 8 + hi * 4) = st;
        }
    }
}

// ---------------- Output projection GEMM ----------------
__global__ __launch_bounds__(256, 3) void gemm_out(
    const ushort* __restrict__ A, const ushort* __restrict__ B,
    const float* __restrict__ bias, float* __restrict__ out)
{
    __shared__ ushort As[128][64];
    __shared__ ushort Bs[128][64];
    const int tid = threadIdx.x;
    const int lane = tid & 63, wave = tid >> 6;
    const int wr = (wave >> 1) * 64, wc = (wave & 1) * 64;
    const int lr = lane & 15, lg = lane >> 4;
    const int swz = (lr & 7) << 4;
    const int sl = lane >> 3;
    const int scol = ((lane & 7) ^ sl) * 8;
    const int rowBase = blockIdx.y * 128, colBase = blockIdx.x * 128;

    f32x4 acc[4][4] = {};
    for (int k0 = 0; k0 < 1024; k0 += 64) {
        __syncthreads();
        int s0 = wave * 4;
#pragma unroll
        for (int i = 0; i < 4; ++i) {
            int s = s0 + i;
            gld_lds16(A + (size_t)(rowBase + s * 8 + sl) * 1024 + k0 + scol, &As[s * 8][0]);
            gld_lds16(B + (size_t)(colBase + s * 8 + sl) * 1024 + k0 + scol, &Bs[s * 8][0]);
        }
        __syncthreads();
#pragma unroll
        for (int kk = 0; kk < 2; ++kk) {
            bf16x8 af[4], bfr[4];
#pragma unroll
            for (int m = 0; m < 4; ++m)
                af[m] = *(const bf16x8*)((const char*)As + (wr + m * 16 + lr) * 128 + ((kk * 64 + lg * 16) ^ swz));
#pragma unroll
            for (int n = 0; n < 4; ++n)
                bfr[n] = *(const bf16x8*)((const char*)Bs + (wc + n * 16 + lr) * 128 + ((kk * 64 + lg * 16) ^ swz));
#pragma unroll
            for (int m = 0; m < 4; ++m)
#pragma unroll
                for (int n = 0; n < 4; ++n)
                    acc[m][n] = __builtin_amdgcn_mfma_f32_16x16x32_bf16(af[m], bfr[n], acc[m][n], 0, 0, 0);
        }
    }
#pragma unroll
    for (int n = 0; n < 4; ++n) {
        int e = colBase + wc + n * 16 + lr;
        float bv = bias[e];
#pragma unroll
        for (int m = 0; m < 4; ++m) {
#pragma unroll
            for (int j = 0; j < 4; ++j) {
                int row = rowBase + wr + m * 16 + lg * 4 + j;
                out[(size_t)row * 1024 + e] = acc[m][n][j] + bv;
            }
        }
    }
}

extern "C" void kernel_launch(void* const* d_in, const int* in_sizes, int n_in,
                              void* d_out, int out_size, void* d_ws, size_t ws_size,
                              hipStream_t stream) {
    const float* query    = (const float*)d_in[0];
    const float* qkv_proj = (const float*)d_in[1];
    const float* qkv_bias = (const float*)d_in[2];
    const float* out_proj = (const float*)d_in[3];
    const float* out_bias = (const float*)d_in[4];
    float* out = (float*)d_out;

    char* ws = (char*)d_ws;
    ushort* qbf      = (ushort*)ws;                      // 8 MB  query bf16 [4096][1024]
    ushort* wqkv     = (ushort*)(ws + (8ull << 20));     // 6 MB  qkv_proj bf16 [3072][1024]
    ushort* wout     = (ushort*)(ws + (14ull << 20));    // 2 MB  out_proj bf16 [1024][1024]
    ushort* qh       = (ushort*)(ws + (16ull << 20));    // 8 MB  [32][2048][64] (pre-scaled by SCALE*LOG2E)
    ushort* kh       = (ushort*)(ws + (24ull << 20));    // 8 MB  [32][2048][64]
    ushort* vT       = (ushort*)(ws + (32ull << 20));    // 8 MB  [32][64][2048] sigma-permuted cols
    ushort* attn_out = (ushort*)(ws + (40ull << 20));    // 8 MB  [4096][1024]

    cast_fused<<<8192, 256, 0, stream>>>(query, qkv_proj, out_proj, qbf, wqkv, wout);
    gemm_qkv<<<dim3(24, 32), 256, 0, stream>>>(qbf, wqkv, qkv_bias, qh, kh, vT);
    attn_kernel<<<dim3(16, 32), 256, 0, stream>>>(qh, kh, vT, attn_out);
    gemm_out<<<dim3(8, 32), 256, 0, stream>>>(attn_out, wout, out_bias, out);
}

// Round 8
// 120.152 us; speedup vs baseline: 1.7566x; 1.0723x over previous
//
#include <hip/hip_runtime.h>
#include <stdint.h>

#define SCALE 0.125f   // D^-0.5, D=64
#define LOG2E 1.44269504088896340736f
#define QK_SCALE (SCALE * LOG2E)   // S in log2 domain -> bare v_exp_f32

typedef __bf16 bf16x8 __attribute__((ext_vector_type(8)));
typedef float f32x4 __attribute__((ext_vector_type(4)));
typedef float f32x16 __attribute__((ext_vector_type(16)));
typedef unsigned u32x4 __attribute__((ext_vector_type(4)));

__device__ __forceinline__ ushort f2bf(float x) {
    union { float f; unsigned u; } v; v.f = x;
    unsigned r = v.u + 0x7FFFu + ((v.u >> 16) & 1u);  // RNE
    return (ushort)(r >> 16);
}

// async 16B global->LDS
__device__ __forceinline__ void gld_lds16(const void* g, void* l) {
    __builtin_amdgcn_global_load_lds(
        reinterpret_cast<const unsigned __attribute__((address_space(1)))*>(
            reinterpret_cast<uintptr_t>(g)),
        reinterpret_cast<unsigned __attribute__((address_space(3)))*>(
            (unsigned)reinterpret_cast<uintptr_t>(l)),
        16, 0, 0);
}

// ---------------- fused fp32 -> bf16 cast of all three operands ----------------
__global__ __launch_bounds__(256) void cast_fused(const float* __restrict__ s0,
                                                  const float* __restrict__ s1,
                                                  const float* __restrict__ s2,
                                                  ushort* __restrict__ d0,
                                                  ushort* __restrict__ d1,
                                                  ushort* __restrict__ d2) {
    int i = blockIdx.x * 256 + threadIdx.x;
    const float* src; ushort* dst; int idx;
    if (i < 1048576)            { src = s0; dst = d0; idx = i; }
    else if (i < 1048576 + 786432) { src = s1; dst = d1; idx = i - 1048576; }
    else                        { src = s2; dst = d2; idx = i - (1048576 + 786432); }
    float4 v = ((const float4*)src)[idx];
    ushort4 o;
    o.x = f2bf(v.x); o.y = f2bf(v.y); o.z = f2bf(v.z); o.w = f2bf(v.w);
    ((ushort4*)dst)[idx] = o;
}

// ---------------- QKV projection GEMM (which-uniform blocks) ----------------
// vT stored with sequence index bits 2<->3 swapped (sigma involution) so the
// attention PV B-fragment is lane-local.
__global__ __launch_bounds__(256, 3) void gemm_qkv(
    const ushort* __restrict__ A, const ushort* __restrict__ B,
    const float* __restrict__ bias,
    ushort* __restrict__ qh, ushort* __restrict__ kh, ushort* __restrict__ vT)
{
    __shared__ ushort As[128][64];
    __shared__ ushort Bs[128][64];
    const int tid = threadIdx.x;
    const int lane = tid & 63, wave = tid >> 6;
    const int wr = (wave >> 1) * 64, wc = (wave & 1) * 64;
    const int lr = lane & 15, lg = lane >> 4;
    const int swz = (lr & 7) << 4;
    const int sl = lane >> 3;
    const int scol = ((lane & 7) ^ sl) * 8;
    const int rowBase = blockIdx.y * 128;
    const int which = blockIdx.x >> 3;
    const int i0 = (blockIdx.x & 7) * 128;

    f32x4 acc[4][4] = {};
    for (int k0 = 0; k0 < 1024; k0 += 64) {
        __syncthreads();
        int s0 = wave * 4;
#pragma unroll
        for (int i = 0; i < 4; ++i) {
            int s = s0 + i;
            int r = s * 8 + sl;
            gld_lds16(A + (size_t)(rowBase + r) * 1024 + k0 + scol, &As[s * 8][0]);
            gld_lds16(B + (size_t)(3 * (i0 + r) + which) * 1024 + k0 + scol, &Bs[s * 8][0]);
        }
        __syncthreads();
#pragma unroll
        for (int kk = 0; kk < 2; ++kk) {
            bf16x8 af[4], bfr[4];
#pragma unroll
            for (int m = 0; m < 4; ++m)
                af[m] = *(const bf16x8*)((const char*)As + (wr + m * 16 + lr) * 128 + ((kk * 64 + lg * 16) ^ swz));
#pragma unroll
            for (int n = 0; n < 4; ++n)
                bfr[n] = *(const bf16x8*)((const char*)Bs + (wc + n * 16 + lr) * 128 + ((kk * 64 + lg * 16) ^ swz));
#pragma unroll
            for (int m = 0; m < 4; ++m)
#pragma unroll
                for (int n = 0; n < 4; ++n)
                    acc[m][n] = __builtin_amdgcn_mfma_f32_16x16x32_bf16(af[m], bfr[n], acc[m][n], 0, 0, 0);
        }
    }
#pragma unroll
    for (int n = 0; n < 4; ++n) {
        int i = i0 + wc + n * 16 + lr;
        float bv = bias[3 * i + which];
        int h = i >> 6, d = i & 63;
#pragma unroll
        for (int m = 0; m < 4; ++m) {
#pragma unroll
            for (int j = 0; j < 4; ++j) {
                int row = rowBase + wr + m * 16 + lg * 4 + j;
                int l = row >> 1, nb = row & 1;
                int bh = nb * 16 + h;
                float v = acc[m][n][j] + bv;
                if (which == 0)      qh[((size_t)bh * 2048 + l) * 64 + d] = f2bf(v * QK_SCALE);
                else if (which == 1) kh[((size_t)bh * 2048 + l) * 64 + d] = f2bf(v);
                else {
                    int lp = (l & ~12) | ((l & 4) << 1) | ((l & 8) >> 1);  // sigma: swap bits 2,3
                    vT[((size_t)bh * 64 + d) * 2048 + lp] = f2bf(v);
                }
            }
        }
    }
}

// ---------------- Flash attention: 8 waves, dual KV-groups, in-LDS merge ----------------
// Block: 512 thr. group = wave>>2 handles KV tiles [group*16, group*16+16);
// sub = wave&3 owns q-rows qBase + sub*32 + [0,32). Each KV tile staged ONCE per
// block into group-private double buffers. Final combine via LDS (no HBM traffic).
// sc[blk] = mfma_32x32x16(K,Q): lane holds S^T[kv][q=lane&31],
//   kv = blk*32 + (r&3) + 8*(r>>2) + 4*hi. V sigma-permuted => PV B-frag lane-local.
__global__ __launch_bounds__(512, 4) void attn_kernel(
    const ushort* __restrict__ qh, const ushort* __restrict__ kh,
    const ushort* __restrict__ vT, ushort* __restrict__ attn_out)
{
    __shared__ __align__(16) char smem[65536];  // Ks[2g][2buf][64][64] | Vs[...] ; merge overlay
    const int tid = threadIdx.x, lane = tid & 63, wave = tid >> 6;
    const int group = wave >> 2, sub = wave & 3;
    const int l31 = lane & 31, hi = lane >> 5;
    const int swz = (lane & 7) << 4;
    const int b = blockIdx.y;
    const int qBase = blockIdx.x * 128;
    const int qrow = qBase + sub * 32 + l31;
    const int sl = lane >> 3;
    const int scol = ((lane & 7) ^ sl) * 8;
    const size_t kBase = (size_t)b * 2048;
    const size_t vBase = (size_t)b * 64;
    char* Kg = smem + group * 16384;
    char* Vg = smem + 32768 + group * 16384;
    const int tg0 = group * 16;

    // Q B-fragments (col=q=lane&31, k = kk*16 + hi*8 + e), persistent
    bf16x8 qf[4];
#pragma unroll
    for (int kk = 0; kk < 4; ++kk)
        qf[kk] = *(const bf16x8*)(qh + (kBase + qrow) * 64 + kk * 16 + hi * 8);

    f32x16 ot[2] = {};
    float mrun = -1e30f, lsum = 0.f;

    // prologue: stage this group's tile tg0 into buf 0
    {
        int s0 = sub * 2;
#pragma unroll
        for (int i = 0; i < 2; ++i) {
            int s = s0 + i;
            gld_lds16(kh + (kBase + tg0 * 64 + s * 8 + sl) * 64 + scol, Kg + s * 1024);
            gld_lds16(vT + (vBase + s * 8 + sl) * 2048 + tg0 * 64 + scol, Vg + s * 1024);
        }
    }
    __syncthreads();

    int buf = 0;
    for (int t = 0; t < 16; ++t) {
        if (t < 15) {
            int s0 = sub * 2;
#pragma unroll
            for (int i = 0; i < 2; ++i) {
                int s = s0 + i;
                gld_lds16(kh + (kBase + (tg0 + t + 1) * 64 + s * 8 + sl) * 64 + scol,
                          Kg + (buf ^ 1) * 8192 + s * 1024);
                gld_lds16(vT + (vBase + s * 8 + sl) * 2048 + (tg0 + t + 1) * 64 + scol,
                          Vg + (buf ^ 1) * 8192 + s * 1024);
            }
        }
        const char* kb = Kg + buf * 8192;
        const char* vb = Vg + buf * 8192;

        // S^T = K Q^T
        f32x16 sc[2] = {};
        __builtin_amdgcn_s_setprio(1);
#pragma unroll
        for (int blk = 0; blk < 2; ++blk) {
#pragma unroll
            for (int kk = 0; kk < 4; ++kk) {
                bf16x8 kf = *(const bf16x8*)(kb + (blk * 32 + l31) * 128 + ((kk * 32 + hi * 16) ^ swz));
                sc[blk] = __builtin_amdgcn_mfma_f32_32x32x16_bf16(kf, qf[kk], sc[blk], 0, 0, 0);
            }
        }
        __builtin_amdgcn_s_setprio(0);

        // row max: depth-5 tree + cross-half combine
        float tm[8];
#pragma unroll
        for (int i = 0; i < 8; ++i)
            tm[i] = fmaxf(fmaxf(sc[0][i], sc[0][i + 8]), fmaxf(sc[1][i], sc[1][i + 8]));
#pragma unroll
        for (int i = 0; i < 4; ++i)
            tm[i] = fmaxf(tm[i], tm[i + 4]);
        float mx = fmaxf(fmaxf(tm[0], tm[2]), fmaxf(tm[1], tm[3]));
        mx = fmaxf(mx, __shfl_xor(mx, 32));
        if (!__all(mx - mrun <= 8.0f)) {   // defer-max (T13)
            float mnew = fmaxf(mrun, mx);
            float alpha = __builtin_amdgcn_exp2f(mrun - mnew);
            mrun = mnew;
            lsum *= alpha;
#pragma unroll
            for (int blk = 0; blk < 2; ++blk)
#pragma unroll
                for (int r = 0; r < 16; ++r)
                    ot[blk][r] *= alpha;
        }
#pragma unroll
        for (int blk = 0; blk < 2; ++blk)
#pragma unroll
            for (int r = 0; r < 16; ++r)
                sc[blk][r] = __builtin_amdgcn_exp2f(sc[blk][r] - mrun);
        // row sum: depth-5 tree + cross-half combine
        float ts[8];
#pragma unroll
        for (int i = 0; i < 8; ++i)
            ts[i] = (sc[0][i] + sc[0][i + 8]) + (sc[1][i] + sc[1][i + 8]);
#pragma unroll
        for (int i = 0; i < 4; ++i)
            ts[i] += ts[i + 4];
        float rs = (ts[0] + ts[2]) + (ts[1] + ts[3]);
        rs += __shfl_xor(rs, 32);
        lsum += rs;

        // PV: pb[e] = sc[g>>1][8*(g&1)+e] (lane-local, sigma-permuted V)
        __builtin_amdgcn_s_setprio(1);
#pragma unroll
        for (int g = 0; g < 4; ++g) {
            const int blk = g >> 1;
            const int base = (g & 1) * 8;
            unsigned A0, A1, B0, B1;
            asm("v_cvt_pk_bf16_f32 %0, %1, %2" : "=v"(A0) : "v"(sc[blk][base + 0]), "v"(sc[blk][base + 1]));
            asm("v_cvt_pk_bf16_f32 %0, %1, %2" : "=v"(A1) : "v"(sc[blk][base + 2]), "v"(sc[blk][base + 3]));
            asm("v_cvt_pk_bf16_f32 %0, %1, %2" : "=v"(B0) : "v"(sc[blk][base + 4]), "v"(sc[blk][base + 5]));
            asm("v_cvt_pk_bf16_f32 %0, %1, %2" : "=v"(B1) : "v"(sc[blk][base + 6]), "v"(sc[blk][base + 7]));
            u32x4 pw; pw[0] = A0; pw[1] = A1; pw[2] = B0; pw[3] = B1;
            bf16x8 pb = __builtin_bit_cast(bf16x8, pw);
#pragma unroll
            for (int dblk = 0; dblk < 2; ++dblk) {
                bf16x8 vf = *(const bf16x8*)(vb + (dblk * 32 + l31) * 128 + ((g * 32 + hi * 16) ^ swz));
                ot[dblk] = __builtin_amdgcn_mfma_f32_32x32x16_bf16(vf, pb, ot[dblk], 0, 0, 0);
            }
        }
        __builtin_amdgcn_s_setprio(0);
        __syncthreads();
        buf ^= 1;
    }

    // ---- in-LDS merge of the two KV-groups ----
    // overlay: MO[4][32][68] f32 (34816 B) + ML[4*32*2] f32 (at 34816)
    float* MO = (float*)smem;
    float* ML = (float*)(smem + 34816);
    if (group) {
        float* mo = MO + (sub * 32 + l31) * 68;
#pragma unroll
        for (int dblk = 0; dblk < 2; ++dblk)
#pragma unroll
            for (int m = 0; m < 4; ++m) {
                float4 st;
                st.x = ot[dblk][4 * m + 0]; st.y = ot[dblk][4 * m + 1];
                st.z = ot[dblk][4 * m + 2]; st.w = ot[dblk][4 * m + 3];
                *(float4*)(mo + dblk * 32 + m * 8 + hi * 4) = st;
            }
        if (!hi) {
            ML[(sub * 32 + l31) * 2 + 0] = mrun;
            ML[(sub * 32 + l31) * 2 + 1] = lsum;
        }
    }
    __syncthreads();
    if (!group) {
        float m1 = ML[(sub * 32 + l31) * 2 + 0];
        float l1 = ML[(sub * 32 + l31) * 2 + 1];
        float mmax = fmaxf(mrun, m1);
        float w0 = __builtin_amdgcn_exp2f(mrun - mmax);
        float w1 = __builtin_amdgcn_exp2f(m1 - mmax);
        float inv = __builtin_amdgcn_rcpf(lsum * w0 + l1 * w1);
        const float* mo = MO + (sub * 32 + l31) * 68;
        const int nb = b >> 4, h = b & 15;
        const size_t row = (size_t)qrow * 2 + nb;
#pragma unroll
        for (int dblk = 0; dblk < 2; ++dblk) {
#pragma unroll
            for (int m = 0; m < 4; ++m) {
                float4 oo = *(const float4*)(mo + dblk * 32 + m * 8 + hi * 4);
                float a0 = (ot[dblk][4 * m + 0] * w0 + oo.x * w1) * inv;
                float a1 = (ot[dblk][4 * m + 1] * w0 + oo.y * w1) * inv;
                float a2 = (ot[dblk][4 * m + 2] * w0 + oo.z * w1) * inv;
                float a3 = (ot[dblk][4 * m + 3] * w0 + oo.w * w1) * inv;
                unsigned w0p, w1p;
                asm("v_cvt_pk_bf16_f32 %0, %1, %2" : "=v"(w0p) : "v"(a0), "v"(a1));
                asm("v_cvt_pk_bf16_f32 %0, %1, %2" : "=v"(w1p) : "v"(a2), "v"(a3));
                uint2 st; st.x = w0p; st.y = w1p;
                *(uint2*)(attn_out + row * 1024 + h * 64 + dblk * 32 + m * 8 + hi * 4) = st;
            }
        }
    }
}

// ---------------- Output projection GEMM (128x64 tiles, 512 blocks) ----------------
__global__ __launch_bounds__(256, 3) void gemm_out(
    const ushort* __restrict__ A, const ushort* __restrict__ B,
    const float* __restrict__ bias, float* __restrict__ out)
{
    __shared__ ushort As[128][64];
    __shared__ ushort Bs[64][64];
    const int tid = threadIdx.x;
    const int lane = tid & 63, wave = tid >> 6;
    const int wr = (wave >> 1) * 64, wc = (wave & 1) * 32;
    const int lr = lane & 15, lg = lane >> 4;
    const int swz = (lr & 7) << 4;
    const int sl = lane >> 3;
    const int scol = ((lane & 7) ^ sl) * 8;
    const int rowBase = blockIdx.y * 128, colBase = blockIdx.x * 64;

    f32x4 acc[4][2] = {};
    for (int k0 = 0; k0 < 1024; k0 += 64) {
        __syncthreads();
#pragma unroll
        for (int i = 0; i < 6; ++i) {
            int s = wave * 6 + i;   // slabs 0..15 = A, 16..23 = B
            if (s < 16)
                gld_lds16(A + (size_t)(rowBase + s * 8 + sl) * 1024 + k0 + scol, &As[s * 8][0]);
            else
                gld_lds16(B + (size_t)(colBase + (s - 16) * 8 + sl) * 1024 + k0 + scol, &Bs[(s - 16) * 8][0]);
        }
        __syncthreads();
#pragma unroll
        for (int kk = 0; kk < 2; ++kk) {
            bf16x8 af[4], bfr[2];
#pragma unroll
            for (int m = 0; m < 4; ++m)
                af[m] = *(const bf16x8*)((const char*)As + (wr + m * 16 + lr) * 128 + ((kk * 64 + lg * 16) ^ swz));
#pragma unroll
            for (int n = 0; n < 2; ++n)
                bfr[n] = *(const bf16x8*)((const char*)Bs + (wc + n * 16 + lr) * 128 + ((kk * 64 + lg * 16) ^ swz));
#pragma unroll
            for (int m = 0; m < 4; ++m)
#pragma unroll
                for (int n = 0; n < 2; ++n)
                    acc[m][n] = __builtin_amdgcn_mfma_f32_16x16x32_bf16(af[m], bfr[n], acc[m][n], 0, 0, 0);
        }
    }
#pragma unroll
    for (int n = 0; n < 2; ++n) {
        int e = colBase + wc + n * 16 + lr;
        float bv = bias[e];
#pragma unroll
        for (int m = 0; m < 4; ++m) {
#pragma unroll
            for (int j = 0; j < 4; ++j) {
                int row = rowBase + wr + m * 16 + lg * 4 + j;
                out[(size_t)row * 1024 + e] = acc[m][n][j] + bv;
            }
        }
    }
}

extern "C" void kernel_launch(void* const* d_in, const int* in_sizes, int n_in,
                              void* d_out, int out_size, void* d_ws, size_t ws_size,
                              hipStream_t stream) {
    const float* query    = (const float*)d_in[0];
    const float* qkv_proj = (const float*)d_in[1];
    const float* qkv_bias = (const float*)d_in[2];
    const float* out_proj = (const float*)d_in[3];
    const float* out_bias = (const float*)d_in[4];
    float* out = (float*)d_out;

    char* ws = (char*)d_ws;
    ushort* qbf      = (ushort*)ws;                      // 8 MB  query bf16 [4096][1024]
    ushort* wqkv     = (ushort*)(ws + (8ull << 20));     // 6 MB  qkv_proj bf16 [3072][1024]
    ushort* wout     = (ushort*)(ws + (14ull << 20));    // 2 MB  out_proj bf16 [1024][1024]
    ushort* qh       = (ushort*)(ws + (16ull << 20));    // 8 MB  [32][2048][64] (pre-scaled by SCALE*LOG2E)
    ushort* kh       = (ushort*)(ws + (24ull << 20));    // 8 MB  [32][2048][64]
    ushort* vT       = (ushort*)(ws + (32ull << 20));    // 8 MB  [32][64][2048] sigma-permuted cols
    ushort* attn_out = (ushort*)(ws + (40ull << 20));    // 8 MB  [4096][1024]

    cast_fused<<<8192, 256, 0, stream>>>(query, qkv_proj, out_proj, qbf, wqkv, wout);
    gemm_qkv<<<dim3(24, 32), 256, 0, stream>>>(qbf, wqkv, qkv_bias, qh, kh, vT);
    attn_kernel<<<dim3(16, 32), 512, 0, stream>>>(qh, kh, vT, attn_out);
    gemm_out<<<dim3(16, 32), 256, 0, stream>>>(attn_out, wout, out_bias, out);
}